// Round 2
// baseline (524.720 us; speedup 1.0000x reference)
//
#include <hip/hip_runtime.h>

#define THREADS 256
#define IMGS 8

// s_w packed offsets (floats)
#define O_C1W 0
#define O_C1B 150
#define O_FSW 156
#define O_SCW 231
#define O_THW 331
#define O_FOW 431
#define O_GB  581
#define O_C5B 585
#define O_F6B 705
#define SW_SIZE 789

// p1 bf16 layout: channel stride 210 ushorts (105 dwords, mod32=9),
// img stride 1260 ushorts (630 dwords, mod32=22) -> good bank spread
#define P1_CH 210
#define P1_IMG 1260
#define C5_STRIDE 124   // mod32=28 -> 8 imgs hit distinct bank groups

__device__ __forceinline__ float fast_tanh(float v) {
    // tanh(v) = 1 - 2/(e^{2v}+1); inf-safe without clamps (exp->inf => 1, exp->0 => -1)
    float e = __expf(2.f * v);
    return 1.f - __fdividef(2.f, e + 1.f);
}

// bf16 pack/unpack (RN rounding on pack)
__device__ __forceinline__ uint pack_bf2(float a, float b) {
    uint ua = __float_as_uint(a), ub = __float_as_uint(b);
    ua = (ua + 0x7fffu + ((ua >> 16) & 1u)) >> 16;
    ub = (ub + 0x7fffu + ((ub >> 16) & 1u)) & 0xffff0000u;
    return ua | ub;
}
__device__ __forceinline__ ushort f2bf(float a) {
    uint ua = __float_as_uint(a);
    return (ushort)((ua + 0x7fffu + ((ua >> 16) & 1u)) >> 16);
}
__device__ __forceinline__ float bflo(uint w) { return __uint_as_float(w << 16); }
__device__ __forceinline__ float bfhi(uint w) { return __uint_as_float(w & 0xffff0000u); }

// read 6 consecutive bf16 starting at even ushort offset (3 dwords)
__device__ __forceinline__ void load_row6u(float* d, const uint* p) {
    uint u0 = p[0], u1 = p[1], u2 = p[2];
    d[0] = bflo(u0); d[1] = bfhi(u0);
    d[2] = bflo(u1); d[3] = bfhi(u1);
    d[4] = bflo(u2); d[5] = bfhi(u2);
}

// grouped-C3 channel tables
__device__ __forceinline__ int g3_ncin(int o){ return o<6?3:(o<15?4:6); }
__device__ __forceinline__ int g3_wb(int o){ return o<6?O_FSW:(o<12?O_SCW:(o<15?O_THW:O_FOW)); }
__device__ __forceinline__ int g3_bi(int o){ return o<6?0:(o<12?1:(o<15?2:3)); }
__device__ __forceinline__ int g3_ch(int o,int j){
    if (o<6)  return (o+j)%6;
    if (o<12) return (o-6+j)%6;
    if (o<15) return (o-12 + j + (j>=2?1:0))%6;
    return j;
}

__global__ __launch_bounds__(THREADS, 4)
void lenet_fused(const float* __restrict__ x,
                 const float* __restrict__ c1_w, const float* __restrict__ c1_b,
                 const float* __restrict__ fs_w, const float* __restrict__ fs_b,
                 const float* __restrict__ sc_w, const float* __restrict__ sc_b,
                 const float* __restrict__ th_w, const float* __restrict__ th_b,
                 const float* __restrict__ fo_w, const float* __restrict__ fo_b,
                 const float* __restrict__ c5_w, const float* __restrict__ c5_b,
                 const float* __restrict__ f6_w, const float* __restrict__ f6_b,
                 const float* __restrict__ out_w, const float* __restrict__ out_b,
                 float* __restrict__ out)
{
    __shared__ ushort s_p1u[IMGS * P1_IMG];   // 20160 B; f6 (fp32) aliases here after stage 3
    __shared__ float  s_w[SW_SIZE];           // 3156 B
    __shared__ float  s_u[3232 + IMGS * C5_STRIDE]; // 16896 B union:
                                              //   stages 1-2: x as bf16 (4096 dwords)
                                              //   stages 3-5: p2 fp32 [0..3231], c5 [3232..)
    float*  s_p2 = s_u;
    float*  s_c5 = s_u + 3232;
    float*  s_f6 = (float*)s_p1u;             // alias: p1 dead after stage 3

    const int tid = threadIdx.x;
    const int blk = blockIdx.x;

    // ---- stage 0: small weights -> LDS ----
    for (int t=tid; t<150; t+=THREADS) s_w[O_C1W+t]=c1_w[t];
    if (tid<6) s_w[O_C1B+tid]=c1_b[tid];
    for (int t=tid; t<75;  t+=THREADS) s_w[O_FSW+t]=fs_w[t];
    for (int t=tid; t<100; t+=THREADS) s_w[O_SCW+t]=sc_w[t];
    for (int t=tid; t<100; t+=THREADS) s_w[O_THW+t]=th_w[t];
    for (int t=tid; t<150; t+=THREADS) s_w[O_FOW+t]=fo_w[t];
    if (tid==0){ s_w[O_GB+0]=fs_b[0]; s_w[O_GB+1]=sc_b[0]; s_w[O_GB+2]=th_b[0]; s_w[O_GB+3]=fo_b[0]; }
    for (int t=tid; t<120; t+=THREADS) s_w[O_C5B+t]=c5_b[t];
    if (tid<84) s_w[O_F6B+tid]=f6_b[tid];

    // ---- stage 1: x -> LDS as bf16 (coalesced float4 in, uint2 out) ----
    {
        const float4* xg = (const float4*)(x + (size_t)blk*(IMGS*1024));
        uint2* sx = (uint2*)s_u;
        #pragma unroll
        for (int i=0;i<8;i++) {
            float4 v = xg[tid + i*THREADS];
            sx[tid + i*THREADS] = make_uint2(pack_bf2(v.x,v.y), pack_bf2(v.z,v.w));
        }
    }
    __syncthreads();

    // ---- stage 2: conv1(5x5) + tanh + 2x2 avgpool -> s_p1u (bf16) ----
    for (int idx=tid; idx<IMGS*84; idx+=THREADS) {
        const int img = idx/84, r2 = idx%84, c = r2/14, pw = r2%14;
        const uint* xim = (const uint*)s_u + img*512 + pw;  // dword units; row stride 16
        float w[25];
        #pragma unroll
        for (int k=0;k<25;k++) w[k] = s_w[O_C1W + c*25 + k];
        const float bias = s_w[O_C1B + c];
        float win[6][6];
        #pragma unroll
        for (int r=0;r<4;r++) load_row6u(win[r], xim + r*16);
        ushort* p1o = s_p1u + img*P1_IMG + c*P1_CH + pw;
        #pragma unroll
        for (int ph=0; ph<14; ph++) {
            load_row6u(win[(2*ph+4)%6], xim + (2*ph+4)*16);
            load_row6u(win[(2*ph+5)%6], xim + (2*ph+5)*16);
            float s = 0.f;
            #pragma unroll
            for (int dy=0; dy<2; dy++)
            #pragma unroll
            for (int dx=0; dx<2; dx++) {
                float acc = bias;
                #pragma unroll
                for (int ky=0; ky<5; ky++)
                #pragma unroll
                for (int kx=0; kx<5; kx++)
                    acc = fmaf(win[(2*ph+dy+ky)%6][dx+kx], w[ky*5+kx], acc);
                s += fast_tanh(acc);
            }
            p1o[ph*14] = f2bf(0.25f*s);
        }
    }
    __syncthreads();

    // ---- stage 3: grouped C3 + tanh + 2x2 avgpool -> s_p2 (fp32) ----
    for (int idx=tid; idx<IMGS*80; idx+=THREADS) {
        const int img = idx/80, r2 = idx%80, o = r2/5, pw = r2%5;
        const int ncin = g3_ncin(o);
        const int wb   = g3_wb(o);
        const float bias = s_w[O_GB + g3_bi(o)];
        float acc0[10], acc1[10];
        #pragma unroll
        for (int h=0;h<10;h++){ acc0[h]=bias; acc1[h]=bias; }
        for (int j=0;j<ncin;j++) {
            const int ch = g3_ch(o,j);
            const uint* p1c = (const uint*)s_p1u + img*(P1_IMG/2) + ch*(P1_CH/2) + pw;
            float w[25];
            #pragma unroll
            for (int k=0;k<25;k++) w[k] = s_w[wb + j*25 + k];
            #pragma unroll
            for (int r=0;r<14;r++) {
                float row[6];
                load_row6u(row, p1c + r*7);
                #pragma unroll
                for (int ky=0;ky<5;ky++) {
                    const int hh = r - ky;
                    if (hh >= 0 && hh < 10) {
                        float s0=0.f, s1=0.f;
                        #pragma unroll
                        for (int kx=0;kx<5;kx++){
                            s0 = fmaf(row[kx],   w[ky*5+kx], s0);
                            s1 = fmaf(row[kx+1], w[ky*5+kx], s1);
                        }
                        acc0[hh] += s0; acc1[hh] += s1;
                    }
                }
            }
        }
        float* p2o = s_p2 + img*404 + o*25 + pw;
        #pragma unroll
        for (int ph=0; ph<5; ph++) {
            float t = fast_tanh(acc0[2*ph])   + fast_tanh(acc1[2*ph])
                    + fast_tanh(acc0[2*ph+1]) + fast_tanh(acc1[2*ph+1]);
            p2o[ph*5] = 0.25f*t;
        }
    }
    __syncthreads();

    // ---- stage 4: conv5 = 120x400 matvec per image + tanh -> s_c5 ----
    for (int idx=tid; idx<120*IMGS; idx+=THREADS) {
        const int f = idx >> 3, img = idx & 7;
        const float4* wr = (const float4*)(c5_w + f*400);
        const float4* pr = (const float4*)(s_p2 + img*404);
        float a0=0.f,a1=0.f,a2=0.f,a3=0.f;
        #pragma unroll 4
        for (int k=0;k<100;k++) {
            float4 a = wr[k], b = pr[k];
            a0=fmaf(a.x,b.x,a0); a1=fmaf(a.y,b.y,a1);
            a2=fmaf(a.z,b.z,a2); a3=fmaf(a.w,b.w,a3);
        }
        s_c5[img*C5_STRIDE + f] = fast_tanh((a0+a1)+(a2+a3) + s_w[O_C5B + f]);
    }
    __syncthreads();

    // ---- stage 5: f6 (84x120) + tanh -> s_f6 (aliases dead p1) ----
    for (int idx=tid; idx<84*IMGS; idx+=THREADS) {
        const int j = idx >> 3, img = idx & 7;
        const float4* wr = (const float4*)(f6_w + j*120);
        const float4* cr = (const float4*)(s_c5 + img*C5_STRIDE);
        float a0=0.f,a1=0.f,a2=0.f,a3=0.f;
        #pragma unroll
        for (int k=0;k<30;k++) {
            float4 a = wr[k], b = cr[k];
            a0=fmaf(a.x,b.x,a0); a1=fmaf(a.y,b.y,a1);
            a2=fmaf(a.z,b.z,a2); a3=fmaf(a.w,b.w,a3);
        }
        s_f6[img*84 + j] = fast_tanh((a0+a1)+(a2+a3) + s_w[O_F6B + j]);
    }
    __syncthreads();

    // ---- stage 6: out (10x84) -> global ----
    if (tid < 80) {
        const int j = tid >> 3, img = tid & 7;
        const float* wr = out_w + j*84;
        const float* fr = s_f6 + img*84;
        float a0=0.f,a1=0.f,a2=0.f,a3=0.f;
        #pragma unroll
        for (int k=0;k<84;k+=4) {
            a0=fmaf(wr[k],  fr[k],  a0); a1=fmaf(wr[k+1],fr[k+1],a1);
            a2=fmaf(wr[k+2],fr[k+2],a2); a3=fmaf(wr[k+3],fr[k+3],a3);
        }
        out[((size_t)blk*IMGS + img)*10 + j] = (a0+a1)+(a2+a3) + out_b[j];
    }
}

extern "C" void kernel_launch(void* const* d_in, const int* in_sizes, int n_in,
                              void* d_out, int out_size, void* d_ws, size_t ws_size,
                              hipStream_t stream) {
    const float* x    = (const float*)d_in[0];
    const float* c1w  = (const float*)d_in[1];
    const float* c1b  = (const float*)d_in[2];
    const float* fsw  = (const float*)d_in[3];
    const float* fsb  = (const float*)d_in[4];
    const float* scw  = (const float*)d_in[5];
    const float* scb  = (const float*)d_in[6];
    const float* thw  = (const float*)d_in[7];
    const float* thb  = (const float*)d_in[8];
    const float* fow  = (const float*)d_in[9];
    const float* fob  = (const float*)d_in[10];
    const float* c5w  = (const float*)d_in[11];
    const float* c5b  = (const float*)d_in[12];
    const float* f6w  = (const float*)d_in[13];
    const float* f6b  = (const float*)d_in[14];
    const float* outw = (const float*)d_in[15];
    const float* outb = (const float*)d_in[16];
    float* outp = (float*)d_out;

    const int B = in_sizes[0] / 1024;     // 16384
    const int nblk = B / IMGS;            // 2048
    lenet_fused<<<nblk, THREADS, 0, stream>>>(
        x, c1w, c1b, fsw, fsb, scw, scb, thw, thb, fow, fob,
        c5w, c5b, f6w, f6b, outw, outb, outp);
}

// Round 3
// 300.925 us; speedup vs baseline: 1.7437x; 1.7437x over previous
//
#include <hip/hip_runtime.h>

#define THREADS 256
#define IMGS 8

// s_w packed offsets (floats)
#define O_C1W 0
#define O_C1B 150
#define O_FSW 156
#define O_SCW 231
#define O_THW 331
#define O_FOW 431
#define O_GB  581
#define O_C5B 585
#define O_F6B 705
#define SW_SIZE 789

// p1 bf16 layout: channel stride 210 ushorts (105 dwords, mod32=9),
// img stride 1260 ushorts (630 dwords, mod32=22) -> good bank spread
#define P1_CH 210
#define P1_IMG 1260
#define C5_STRIDE 124   // mod32=28 -> 8 imgs hit distinct bank groups

__device__ __forceinline__ float fast_tanh(float v) {
    // tanh(v) = 1 - 2/(e^{2v}+1); inf-safe without clamps (exp->inf => 1, exp->0 => -1)
    float e = __expf(2.f * v);
    return 1.f - __fdividef(2.f, e + 1.f);
}

// bf16 pack/unpack (RN rounding on pack)
__device__ __forceinline__ uint pack_bf2(float a, float b) {
    uint ua = __float_as_uint(a), ub = __float_as_uint(b);
    ua = (ua + 0x7fffu + ((ua >> 16) & 1u)) >> 16;
    ub = (ub + 0x7fffu + ((ub >> 16) & 1u)) & 0xffff0000u;
    return ua | ub;
}
__device__ __forceinline__ ushort f2bf(float a) {
    uint ua = __float_as_uint(a);
    return (ushort)((ua + 0x7fffu + ((ua >> 16) & 1u)) >> 16);
}
__device__ __forceinline__ float bflo(uint w) { return __uint_as_float(w << 16); }
__device__ __forceinline__ float bfhi(uint w) { return __uint_as_float(w & 0xffff0000u); }

// read 6 consecutive bf16 starting at even ushort offset (3 dwords)
__device__ __forceinline__ void load_row6u(float* d, const uint* p) {
    uint u0 = p[0], u1 = p[1], u2 = p[2];
    d[0] = bflo(u0); d[1] = bfhi(u0);
    d[2] = bflo(u1); d[3] = bfhi(u1);
    d[4] = bflo(u2); d[5] = bfhi(u2);
}

// grouped-C3 channel tables
__device__ __forceinline__ int g3_ncin(int o){ return o<6?3:(o<15?4:6); }
__device__ __forceinline__ int g3_wb(int o){ return o<6?O_FSW:(o<12?O_SCW:(o<15?O_THW:O_FOW)); }
__device__ __forceinline__ int g3_bi(int o){ return o<6?0:(o<12?1:(o<15?2:3)); }
__device__ __forceinline__ int g3_ch(int o,int j){
    if (o<6)  return (o+j)%6;
    if (o<12) return (o-6+j)%6;
    if (o<15) return (o-12 + j + (j>=2?1:0))%6;
    return j;
}

__global__ __launch_bounds__(THREADS)
void lenet_fused(const float* __restrict__ x,
                 const float* __restrict__ c1_w, const float* __restrict__ c1_b,
                 const float* __restrict__ fs_w, const float* __restrict__ fs_b,
                 const float* __restrict__ sc_w, const float* __restrict__ sc_b,
                 const float* __restrict__ th_w, const float* __restrict__ th_b,
                 const float* __restrict__ fo_w, const float* __restrict__ fo_b,
                 const float* __restrict__ c5_w, const float* __restrict__ c5_b,
                 const float* __restrict__ f6_w, const float* __restrict__ f6_b,
                 const float* __restrict__ out_w, const float* __restrict__ out_b,
                 float* __restrict__ out)
{
    __shared__ ushort s_p1u[IMGS * P1_IMG];   // 20160 B; f6 (fp32) aliases here after stage 3
    __shared__ float  s_w[SW_SIZE];           // 3156 B
    __shared__ float  s_u[3232 + IMGS * C5_STRIDE]; // 16896 B union:
                                              //   stages 1-2: x as bf16 (4096 dwords)
                                              //   stages 3-5: p2 fp32 [0..3231], c5 [3232..)
    float*  s_p2 = s_u;
    float*  s_c5 = s_u + 3232;
    float*  s_f6 = (float*)s_p1u;             // alias: p1 dead after stage 3

    const int tid = threadIdx.x;
    const int blk = blockIdx.x;

    // ---- stage 0: small weights -> LDS ----
    for (int t=tid; t<150; t+=THREADS) s_w[O_C1W+t]=c1_w[t];
    if (tid<6) s_w[O_C1B+tid]=c1_b[tid];
    for (int t=tid; t<75;  t+=THREADS) s_w[O_FSW+t]=fs_w[t];
    for (int t=tid; t<100; t+=THREADS) s_w[O_SCW+t]=sc_w[t];
    for (int t=tid; t<100; t+=THREADS) s_w[O_THW+t]=th_w[t];
    for (int t=tid; t<150; t+=THREADS) s_w[O_FOW+t]=fo_w[t];
    if (tid==0){ s_w[O_GB+0]=fs_b[0]; s_w[O_GB+1]=sc_b[0]; s_w[O_GB+2]=th_b[0]; s_w[O_GB+3]=fo_b[0]; }
    for (int t=tid; t<120; t+=THREADS) s_w[O_C5B+t]=c5_b[t];
    if (tid<84) s_w[O_F6B+tid]=f6_b[tid];

    // ---- stage 1: x -> LDS as bf16 (coalesced float4 in, uint2 out) ----
    {
        const float4* xg = (const float4*)(x + (size_t)blk*(IMGS*1024));
        uint2* sx = (uint2*)s_u;
        #pragma unroll
        for (int i=0;i<8;i++) {
            float4 v = xg[tid + i*THREADS];
            sx[tid + i*THREADS] = make_uint2(pack_bf2(v.x,v.y), pack_bf2(v.z,v.w));
        }
    }
    __syncthreads();

    // ---- stage 2: conv1(5x5) + tanh + 2x2 avgpool -> s_p1u (bf16) ----
    for (int idx=tid; idx<IMGS*84; idx+=THREADS) {
        const int img = idx/84, r2 = idx%84, c = r2/14, pw = r2%14;
        const uint* xim = (const uint*)s_u + img*512 + pw;  // dword units; row stride 16
        float w[25];
        #pragma unroll
        for (int k=0;k<25;k++) w[k] = s_w[O_C1W + c*25 + k];
        const float bias = s_w[O_C1B + c];
        float win[6][6];
        #pragma unroll
        for (int r=0;r<4;r++) load_row6u(win[r], xim + r*16);
        ushort* p1o = s_p1u + img*P1_IMG + c*P1_CH + pw;
        #pragma unroll
        for (int ph=0; ph<14; ph++) {
            load_row6u(win[(2*ph+4)%6], xim + (2*ph+4)*16);
            load_row6u(win[(2*ph+5)%6], xim + (2*ph+5)*16);
            float s = 0.f;
            #pragma unroll
            for (int dy=0; dy<2; dy++)
            #pragma unroll
            for (int dx=0; dx<2; dx++) {
                float acc = bias;
                #pragma unroll
                for (int ky=0; ky<5; ky++)
                #pragma unroll
                for (int kx=0; kx<5; kx++)
                    acc = fmaf(win[(2*ph+dy+ky)%6][dx+kx], w[ky*5+kx], acc);
                s += fast_tanh(acc);
            }
            p1o[ph*14] = f2bf(0.25f*s);
        }
    }
    __syncthreads();

    // ---- stage 3: grouped C3 + tanh + 2x2 avgpool -> s_p2 (fp32) ----
    for (int idx=tid; idx<IMGS*80; idx+=THREADS) {
        const int img = idx/80, r2 = idx%80, o = r2/5, pw = r2%5;
        const int ncin = g3_ncin(o);
        const int wb   = g3_wb(o);
        const float bias = s_w[O_GB + g3_bi(o)];
        float acc0[10], acc1[10];
        #pragma unroll
        for (int h=0;h<10;h++){ acc0[h]=bias; acc1[h]=bias; }
        for (int j=0;j<ncin;j++) {
            const int ch = g3_ch(o,j);
            const uint* p1c = (const uint*)s_p1u + img*(P1_IMG/2) + ch*(P1_CH/2) + pw;
            float w[25];
            #pragma unroll
            for (int k=0;k<25;k++) w[k] = s_w[wb + j*25 + k];
            #pragma unroll
            for (int r=0;r<14;r++) {
                float row[6];
                load_row6u(row, p1c + r*7);
                #pragma unroll
                for (int ky=0;ky<5;ky++) {
                    const int hh = r - ky;
                    if (hh >= 0 && hh < 10) {
                        float s0=0.f, s1=0.f;
                        #pragma unroll
                        for (int kx=0;kx<5;kx++){
                            s0 = fmaf(row[kx],   w[ky*5+kx], s0);
                            s1 = fmaf(row[kx+1], w[ky*5+kx], s1);
                        }
                        acc0[hh] += s0; acc1[hh] += s1;
                    }
                }
            }
        }
        float* p2o = s_p2 + img*404 + o*25 + pw;
        #pragma unroll
        for (int ph=0; ph<5; ph++) {
            float t = fast_tanh(acc0[2*ph])   + fast_tanh(acc1[2*ph])
                    + fast_tanh(acc0[2*ph+1]) + fast_tanh(acc1[2*ph+1]);
            p2o[ph*5] = 0.25f*t;
        }
    }
    __syncthreads();

    // ---- stage 4: conv5 = 120x400 matvec per image + tanh -> s_c5 ----
    for (int idx=tid; idx<120*IMGS; idx+=THREADS) {
        const int f = idx >> 3, img = idx & 7;
        const float4* wr = (const float4*)(c5_w + f*400);
        const float4* pr = (const float4*)(s_p2 + img*404);
        float a0=0.f,a1=0.f,a2=0.f,a3=0.f;
        #pragma unroll 4
        for (int k=0;k<100;k++) {
            float4 a = wr[k], b = pr[k];
            a0=fmaf(a.x,b.x,a0); a1=fmaf(a.y,b.y,a1);
            a2=fmaf(a.z,b.z,a2); a3=fmaf(a.w,b.w,a3);
        }
        s_c5[img*C5_STRIDE + f] = fast_tanh((a0+a1)+(a2+a3) + s_w[O_C5B + f]);
    }
    __syncthreads();

    // ---- stage 5: f6 (84x120) + tanh -> s_f6 (aliases dead p1) ----
    for (int idx=tid; idx<84*IMGS; idx+=THREADS) {
        const int j = idx >> 3, img = idx & 7;
        const float4* wr = (const float4*)(f6_w + j*120);
        const float4* cr = (const float4*)(s_c5 + img*C5_STRIDE);
        float a0=0.f,a1=0.f,a2=0.f,a3=0.f;
        #pragma unroll
        for (int k=0;k<30;k++) {
            float4 a = wr[k], b = cr[k];
            a0=fmaf(a.x,b.x,a0); a1=fmaf(a.y,b.y,a1);
            a2=fmaf(a.z,b.z,a2); a3=fmaf(a.w,b.w,a3);
        }
        s_f6[img*84 + j] = fast_tanh((a0+a1)+(a2+a3) + s_w[O_F6B + j]);
    }
    __syncthreads();

    // ---- stage 6: out (10x84) -> global ----
    if (tid < 80) {
        const int j = tid >> 3, img = tid & 7;
        const float* wr = out_w + j*84;
        const float* fr = s_f6 + img*84;
        float a0=0.f,a1=0.f,a2=0.f,a3=0.f;
        #pragma unroll
        for (int k=0;k<84;k+=4) {
            a0=fmaf(wr[k],  fr[k],  a0); a1=fmaf(wr[k+1],fr[k+1],a1);
            a2=fmaf(wr[k+2],fr[k+2],a2); a3=fmaf(wr[k+3],fr[k+3],a3);
        }
        out[((size_t)blk*IMGS + img)*10 + j] = (a0+a1)+(a2+a3) + out_b[j];
    }
}

extern "C" void kernel_launch(void* const* d_in, const int* in_sizes, int n_in,
                              void* d_out, int out_size, void* d_ws, size_t ws_size,
                              hipStream_t stream) {
    const float* x    = (const float*)d_in[0];
    const float* c1w  = (const float*)d_in[1];
    const float* c1b  = (const float*)d_in[2];
    const float* fsw  = (const float*)d_in[3];
    const float* fsb  = (const float*)d_in[4];
    const float* scw  = (const float*)d_in[5];
    const float* scb  = (const float*)d_in[6];
    const float* thw  = (const float*)d_in[7];
    const float* thb  = (const float*)d_in[8];
    const float* fow  = (const float*)d_in[9];
    const float* fob  = (const float*)d_in[10];
    const float* c5w  = (const float*)d_in[11];
    const float* c5b  = (const float*)d_in[12];
    const float* f6w  = (const float*)d_in[13];
    const float* f6b  = (const float*)d_in[14];
    const float* outw = (const float*)d_in[15];
    const float* outb = (const float*)d_in[16];
    float* outp = (float*)d_out;

    const int B = in_sizes[0] / 1024;     // 16384
    const int nblk = B / IMGS;            // 2048
    lenet_fused<<<nblk, THREADS, 0, stream>>>(
        x, c1w, c1b, fsw, fsb, scw, scb, thw, thb, fow, fob,
        c5w, c5b, f6w, f6b, outw, outb, outp);
}

// Round 4
// 256.425 us; speedup vs baseline: 2.0463x; 1.1735x over previous
//
#include <hip/hip_runtime.h>

#define THREADS 256
#define IMGS 8

// s_w (fp32) offsets
#define O_C1B 0
#define O_GB  6
#define O_C5B 10
#define O_F6B 130
#define SW_SIZE 214

// p1 fp16 layout: ch stride 104 uints (208 halves), img stride 624 uints
#define P1_CHU 104
#define P1_IMGU 624
#define C5_STRIDE 124

typedef _Float16 h2 __attribute__((ext_vector_type(2)));

__device__ __forceinline__ float fdot2(uint a, uint b, float c) {
    return __builtin_amdgcn_fdot2(__builtin_bit_cast(h2, a), __builtin_bit_cast(h2, b), c, false);
}
__device__ __forceinline__ uint pkh2(float a, float b) {
    return __builtin_bit_cast(uint, __builtin_amdgcn_cvt_pkrtz(a, b));
}
__device__ __forceinline__ ushort f16b(float a) {
    return (ushort)(pkh2(a, 0.f) & 0xffffu);
}

__device__ __forceinline__ float fast_tanh(float v) {
    float e = __expf(2.f * v);
    return 1.f - __fdividef(2.f, e + 1.f);
}

// load one 6-half row: q = aligned pairs (h0h1)(h2h3)(h4h5), s = shifted (h1h2)(h3h4)(h5,0)
__device__ __forceinline__ void ld_row(const uint* p, uint* q, uint* s) {
    uint a = p[0], b = p[1], c = p[2];
    q[0] = a; q[1] = b; q[2] = c;
    s[0] = (b << 16) | (a >> 16);
    s[1] = (c << 16) | (b >> 16);
    s[2] = c >> 16;
}

// grouped-C3 tables
__device__ __forceinline__ int g3_ncin(int o){ return o<6?3:(o<15?4:6); }
__device__ __forceinline__ int g3_slot(int o,int j){
    return o<6 ? 6+j : (o<12 ? 9+j : (o<15 ? 13+j : 17+j));
}
__device__ __forceinline__ int g3_bi(int o){ return o<6?0:(o<12?1:(o<15?2:3)); }
__device__ __forceinline__ int g3_ch(int o,int j){
    if (o<6)  return (o+j)%6;
    if (o<12) return (o-6+j)%6;
    if (o<15) return (o-12 + j + (j>=2?1:0))%6;
    return j;
}

__global__ __launch_bounds__(THREADS)
void lenet_fused(const float* __restrict__ x,
                 const float* __restrict__ c1_w, const float* __restrict__ c1_b,
                 const float* __restrict__ fs_w, const float* __restrict__ fs_b,
                 const float* __restrict__ sc_w, const float* __restrict__ sc_b,
                 const float* __restrict__ th_w, const float* __restrict__ th_b,
                 const float* __restrict__ fo_w, const float* __restrict__ fo_b,
                 const float* __restrict__ c5_w, const float* __restrict__ c5_b,
                 const float* __restrict__ f6_w, const float* __restrict__ f6_b,
                 const float* __restrict__ out_w, const float* __restrict__ out_b,
                 float* __restrict__ out)
{
    __shared__ uint  s_p1h[IMGS * P1_IMGU];   // 19968 B; f6 (fp32) aliases after stage 3
    __shared__ uint  s_whu[23 * 16];          // 1472 B packed fp16 weights (row-padded)
    __shared__ float s_w[SW_SIZE];            // 856 B fp32 biases
    __shared__ float s_u[3232 + IMGS * C5_STRIDE]; // 16896 B union:
                                              //   stages 1-2: x fp16 (4096 uints)
                                              //   stages 3-5: p2 fp32, c5 fp32
    uint*  s_xh = (uint*)s_u;
    float* s_p2 = s_u;
    float* s_c5 = s_u + 3232;
    float* s_f6 = (float*)s_p1h;

    const int tid = threadIdx.x;
    const int blk = blockIdx.x;

    // ---- stage 0a: fp32 biases -> LDS ----
    if (tid < 6)  s_w[O_C1B + tid] = c1_b[tid];
    if (tid == 0){ s_w[O_GB+0]=fs_b[0]; s_w[O_GB+1]=sc_b[0]; s_w[O_GB+2]=th_b[0]; s_w[O_GB+3]=fo_b[0]; }
    if (tid < 120) s_w[O_C5B + tid] = c5_b[tid];
    if (tid < 84)  s_w[O_F6B + tid] = f6_b[tid];

    // ---- stage 0b: conv weights -> packed fp16, row-padded (slot = 16 uints) ----
    if (tid < 23) {
        const float* src;
        if      (tid < 6)  src = c1_w + tid*25;
        else if (tid < 9)  src = fs_w + (tid-6)*25;
        else if (tid < 13) src = sc_w + (tid-9)*25;
        else if (tid < 17) src = th_w + (tid-13)*25;
        else               src = fo_w + (tid-17)*25;
        uint* dst = s_whu + tid*16;
        #pragma unroll
        for (int ky=0; ky<5; ky++) {
            dst[ky*3+0] = pkh2(src[ky*5+0], src[ky*5+1]);
            dst[ky*3+1] = pkh2(src[ky*5+2], src[ky*5+3]);
            dst[ky*3+2] = pkh2(src[ky*5+4], 0.f);
        }
    }

    // ---- stage 1: x -> LDS as fp16 pairs ----
    {
        const float4* xg = (const float4*)(x + (size_t)blk*(IMGS*1024));
        uint2* sx = (uint2*)s_u;
        #pragma unroll
        for (int i=0;i<8;i++) {
            float4 v = xg[tid + i*THREADS];
            sx[tid + i*THREADS] = make_uint2(pkh2(v.x,v.y), pkh2(v.z,v.w));
        }
    }
    __syncthreads();

    // ---- stage 2: conv1 + tanh + 2x2 avgpool -> s_p1h (fp16) ----
    for (int idx=tid; idx<IMGS*84; idx+=THREADS) {
        const int img = idx/84, r2 = idx%84, c = r2/14, pw = r2%14;
        const uint* xim = s_xh + img*512 + pw;   // uint units; row stride 16
        uint wp[5][3];
        #pragma unroll
        for (int k=0;k<15;k++) ((uint*)wp)[k] = s_whu[c*16 + k];
        const float bias = s_w[O_C1B + c];
        uint q[6][3], s[6][3];
        #pragma unroll
        for (int r=0;r<4;r++) ld_row(xim + r*16, q[r], s[r]);
        ushort* p1o = (ushort*)s_p1h + img*(P1_IMGU*2) + c*(P1_CHU*2) + pw;
        #pragma unroll
        for (int ph=0; ph<14; ph++) {
            ld_row(xim + (2*ph+4)*16, q[(2*ph+4)%6], s[(2*ph+4)%6]);
            ld_row(xim + (2*ph+5)*16, q[(2*ph+5)%6], s[(2*ph+5)%6]);
            float sum = 0.f;
            #pragma unroll
            for (int dy=0; dy<2; dy++)
            #pragma unroll
            for (int dx=0; dx<2; dx++) {
                float t = bias;
                #pragma unroll
                for (int ky=0; ky<5; ky++) {
                    const int sl = (2*ph+dy+ky)%6;
                    const uint* rr = dx ? s[sl] : q[sl];
                    t = fdot2(rr[0], wp[ky][0], t);
                    t = fdot2(rr[1], wp[ky][1], t);
                    t = fdot2(rr[2], wp[ky][2], t);
                }
                sum += fast_tanh(t);
            }
            p1o[ph*14] = f16b(0.25f*sum);
        }
    }
    __syncthreads();

    // ---- stage 3: grouped C3 + tanh + 2x2 avgpool -> s_p2 (fp32) ----
    // o-major item order: waves have uniform channel counts (no trip divergence)
    for (int idx=tid; idx<IMGS*80; idx+=THREADS) {
        const int o = idx/40, r2 = idx%40, img = r2/5, pw = r2%5;
        const int ncin = g3_ncin(o);
        const float bias = s_w[O_GB + g3_bi(o)];
        float acc0[10], acc1[10];
        #pragma unroll
        for (int h=0;h<10;h++){ acc0[h]=bias; acc1[h]=bias; }
        for (int j=0;j<ncin;j++) {
            const uint* p1c = s_p1h + img*P1_IMGU + g3_ch(o,j)*P1_CHU + pw;
            uint wp[5][3];
            const int slot = g3_slot(o,j);
            #pragma unroll
            for (int k=0;k<15;k++) ((uint*)wp)[k] = s_whu[slot*16 + k];
            #pragma unroll
            for (int r=0;r<14;r++) {
                uint a = p1c[r*7], b = p1c[r*7+1], cc = p1c[r*7+2];
                uint s0 = (b << 16) | (a >> 16);
                uint s1 = (cc << 16) | (b >> 16);
                uint s2 = cc >> 16;
                #pragma unroll
                for (int ky=0;ky<5;ky++) {
                    const int hh = r - ky;
                    if (hh >= 0 && hh < 10) {
                        acc0[hh] = fdot2(cc, wp[ky][2], fdot2(b,  wp[ky][1], fdot2(a,  wp[ky][0], acc0[hh])));
                        acc1[hh] = fdot2(s2, wp[ky][2], fdot2(s1, wp[ky][1], fdot2(s0, wp[ky][0], acc1[hh])));
                    }
                }
            }
        }
        float* p2o = s_p2 + img*404 + o*25 + pw;
        #pragma unroll
        for (int ph=0; ph<5; ph++) {
            float t = fast_tanh(acc0[2*ph])   + fast_tanh(acc1[2*ph])
                    + fast_tanh(acc0[2*ph+1]) + fast_tanh(acc1[2*ph+1]);
            p2o[ph*5] = 0.25f*t;
        }
    }
    __syncthreads();

    // ---- stage 4: conv5 = 120x400 matvec per image + tanh -> s_c5 ----
    for (int idx=tid; idx<120*IMGS; idx+=THREADS) {
        const int f = idx >> 3, img = idx & 7;
        const float4* wr = (const float4*)(c5_w + f*400);
        const float4* pr = (const float4*)(s_p2 + img*404);
        float a0=0.f,a1=0.f,a2=0.f,a3=0.f;
        #pragma unroll 4
        for (int k=0;k<100;k++) {
            float4 a = wr[k], b = pr[k];
            a0=fmaf(a.x,b.x,a0); a1=fmaf(a.y,b.y,a1);
            a2=fmaf(a.z,b.z,a2); a3=fmaf(a.w,b.w,a3);
        }
        s_c5[img*C5_STRIDE + f] = fast_tanh((a0+a1)+(a2+a3) + s_w[O_C5B + f]);
    }
    __syncthreads();

    // ---- stage 5: f6 (84x120) + tanh -> s_f6 (aliases dead p1) ----
    for (int idx=tid; idx<84*IMGS; idx+=THREADS) {
        const int j = idx >> 3, img = idx & 7;
        const float4* wr = (const float4*)(f6_w + j*120);
        const float4* cr = (const float4*)(s_c5 + img*C5_STRIDE);
        float a0=0.f,a1=0.f,a2=0.f,a3=0.f;
        #pragma unroll
        for (int k=0;k<30;k++) {
            float4 a = wr[k], b = cr[k];
            a0=fmaf(a.x,b.x,a0); a1=fmaf(a.y,b.y,a1);
            a2=fmaf(a.z,b.z,a2); a3=fmaf(a.w,b.w,a3);
        }
        s_f6[img*84 + j] = fast_tanh((a0+a1)+(a2+a3) + s_w[O_F6B + j]);
    }
    __syncthreads();

    // ---- stage 6: out (10x84) -> global ----
    if (tid < 80) {
        const int j = tid >> 3, img = tid & 7;
        const float* wr = out_w + j*84;
        const float* fr = s_f6 + img*84;
        float a0=0.f,a1=0.f,a2=0.f,a3=0.f;
        #pragma unroll
        for (int k=0;k<84;k+=4) {
            a0=fmaf(wr[k],  fr[k],  a0); a1=fmaf(wr[k+1],fr[k+1],a1);
            a2=fmaf(wr[k+2],fr[k+2],a2); a3=fmaf(wr[k+3],fr[k+3],a3);
        }
        out[((size_t)blk*IMGS + img)*10 + j] = (a0+a1)+(a2+a3) + out_b[j];
    }
}

extern "C" void kernel_launch(void* const* d_in, const int* in_sizes, int n_in,
                              void* d_out, int out_size, void* d_ws, size_t ws_size,
                              hipStream_t stream) {
    const float* x    = (const float*)d_in[0];
    const float* c1w  = (const float*)d_in[1];
    const float* c1b  = (const float*)d_in[2];
    const float* fsw  = (const float*)d_in[3];
    const float* fsb  = (const float*)d_in[4];
    const float* scw  = (const float*)d_in[5];
    const float* scb  = (const float*)d_in[6];
    const float* thw  = (const float*)d_in[7];
    const float* thb  = (const float*)d_in[8];
    const float* fow  = (const float*)d_in[9];
    const float* fob  = (const float*)d_in[10];
    const float* c5w  = (const float*)d_in[11];
    const float* c5b  = (const float*)d_in[12];
    const float* f6w  = (const float*)d_in[13];
    const float* f6b  = (const float*)d_in[14];
    const float* outw = (const float*)d_in[15];
    const float* outb = (const float*)d_in[16];
    float* outp = (float*)d_out;

    const int B = in_sizes[0] / 1024;     // 16384
    const int nblk = B / IMGS;            // 2048
    lenet_fused<<<nblk, THREADS, 0, stream>>>(
        x, c1w, c1b, fsw, fsb, scw, scb, thw, thb, fow, fob,
        c5w, c5b, f6w, f6b, outw, outb, outp);
}

// Round 6
// 217.772 us; speedup vs baseline: 2.4095x; 1.1775x over previous
//
#include <hip/hip_runtime.h>

#define THREADS 256
#define IMGS 8

// fp32 bias offsets in s_w
#define O_C1B 0
#define O_GB  6
#define O_C5B 10
#define O_F6B 130
#define SW_SIZE 214

// p1 fp16 layout (uint units): ch stride mod32=9, img stride mod32=22 -> full bank spread
#define P1_CHU 105
#define P1_IMGU 630
// p2 fp16: 201 uints/img (402 halves, 400 used), mod32=9
#define P2_IMGU 201
// c5 fp16: 61 uints/img (122 halves, 120 used)
#define C5_IMGU 61

typedef _Float16 h2 __attribute__((ext_vector_type(2)));

__device__ __forceinline__ float fdot2(uint a, uint b, float c) {
    return __builtin_amdgcn_fdot2(__builtin_bit_cast(h2, a), __builtin_bit_cast(h2, b), c, false);
}
__device__ __forceinline__ uint pkh2(float a, float b) {
    return __builtin_bit_cast(uint, __builtin_amdgcn_cvt_pkrtz(a, b));
}
__device__ __forceinline__ ushort f16rn(float a) {
    _Float16 h = (_Float16)a;
    return __builtin_bit_cast(ushort, h);
}

__device__ __forceinline__ float fast_tanh(float v) {
    float e = __expf(2.f * v);
    return 1.f - __fdividef(2.f, e + 1.f);
}

// load one 6-half row: q = aligned pairs, s = shifted-by-1 pairs
__device__ __forceinline__ void ld_row(const uint* p, uint* q, uint* s) {
    uint a = p[0], b = p[1], c = p[2];
    q[0] = a; q[1] = b; q[2] = c;
    s[0] = (b << 16) | (a >> 16);
    s[1] = (c << 16) | (b >> 16);
    s[2] = c >> 16;
}

// grouped-C3 tables
__device__ __forceinline__ int g3_ncin(int o){ return o<6?3:(o<15?4:6); }
__device__ __forceinline__ int g3_slot(int o,int j){
    return o<6 ? 6+j : (o<12 ? 9+j : (o<15 ? 13+j : 17+j));
}
__device__ __forceinline__ int g3_bi(int o){ return o<6?0:(o<12?1:(o<15?2:3)); }
__device__ __forceinline__ int g3_ch(int o,int j){
    if (o<6)  return (o+j)%6;
    if (o<12) return (o-6+j)%6;
    if (o<15) return (o-12 + j + (j>=2?1:0))%6;
    return j;
}

// pre-kernel: convert c5_w / f6_w to fp16 in workspace (RN)
__global__ __launch_bounds__(256)
void cvt_w16(const float* __restrict__ c5w, const float* __restrict__ f6w,
             ushort* __restrict__ ws) {
    int i = blockIdx.x * 256 + threadIdx.x;
    if (i < 48000) ws[i] = f16rn(c5w[i]);
    if (i < 10080) ws[48000 + i] = f16rn(f6w[i]);
}

template<bool H>
__global__ __launch_bounds__(THREADS)
void lenet_fused(const float* __restrict__ x,
                 const float* __restrict__ c1_w, const float* __restrict__ c1_b,
                 const float* __restrict__ fs_w, const float* __restrict__ fs_b,
                 const float* __restrict__ sc_w, const float* __restrict__ sc_b,
                 const float* __restrict__ th_w, const float* __restrict__ th_b,
                 const float* __restrict__ fo_w, const float* __restrict__ fo_b,
                 const float* __restrict__ c5_w, const float* __restrict__ c5_b,
                 const float* __restrict__ f6_w, const float* __restrict__ f6_b,
                 const float* __restrict__ out_w, const float* __restrict__ out_b,
                 const ushort* __restrict__ wsh,
                 float* __restrict__ out)
{
    __shared__ uint  s_p1h[IMGS * P1_IMGU];   // 20160 B; f6 (fp32) aliases after stage 4
    __shared__ uint  s_whu[23 * 16];          // packed fp16 conv weights (row-padded)
    __shared__ float s_w[SW_SIZE];            // fp32 biases
    __shared__ uint  s_u[4096];               // 16 KB union:
                                              //  stages 1-2: x fp16 (4096 uints)
                                              //  stages 3-5: p2h [0..1607], c5h [1608..2095]
    uint*  s_xh  = s_u;
    uint*  s_c5u = s_u + IMGS * P2_IMGU;
    float* s_f6  = (float*)s_p1h;

    const int tid = threadIdx.x;
    const int blk = blockIdx.x;

    // ---- stage 0a: fp32 biases -> LDS ----
    if (tid < 6)  s_w[O_C1B + tid] = c1_b[tid];
    if (tid == 0){ s_w[O_GB+0]=fs_b[0]; s_w[O_GB+1]=sc_b[0]; s_w[O_GB+2]=th_b[0]; s_w[O_GB+3]=fo_b[0]; }
    if (tid < 120) s_w[O_C5B + tid] = c5_b[tid];
    if (tid < 84)  s_w[O_F6B + tid] = f6_b[tid];

    // ---- stage 0b: conv weights -> packed fp16, row-padded (slot = 16 uints) ----
    if (tid < 23) {
        const float* src;
        if      (tid < 6)  src = c1_w + tid*25;
        else if (tid < 9)  src = fs_w + (tid-6)*25;
        else if (tid < 13) src = sc_w + (tid-9)*25;
        else if (tid < 17) src = th_w + (tid-13)*25;
        else               src = fo_w + (tid-17)*25;
        uint* dst = s_whu + tid*16;
        #pragma unroll
        for (int ky=0; ky<5; ky++) {
            dst[ky*3+0] = pkh2(src[ky*5+0], src[ky*5+1]);
            dst[ky*3+1] = pkh2(src[ky*5+2], src[ky*5+3]);
            dst[ky*3+2] = pkh2(src[ky*5+4], 0.f);
        }
    }

    // ---- stage 1: x -> LDS as fp16 pairs ----
    {
        const float4* xg = (const float4*)(x + (size_t)blk*(IMGS*1024));
        uint2* sx = (uint2*)s_u;
        #pragma unroll
        for (int i=0;i<8;i++) {
            float4 v = xg[tid + i*THREADS];
            sx[tid + i*THREADS] = make_uint2(pkh2(v.x,v.y), pkh2(v.z,v.w));
        }
    }
    __syncthreads();

    // ---- stage 2: conv1 + tanh + 2x2 avgpool -> s_p1h (fp16) ----
    for (int idx=tid; idx<IMGS*84; idx+=THREADS) {
        const int img = idx/84, r2 = idx%84, c = r2/14, pw = r2%14;
        const uint* xim = s_xh + img*512 + pw;
        uint wp[5][3];
        #pragma unroll
        for (int k=0;k<15;k++) ((uint*)wp)[k] = s_whu[c*16 + k];
        const float bias = s_w[O_C1B + c];
        uint q[6][3], s[6][3];
        #pragma unroll
        for (int r=0;r<4;r++) ld_row(xim + r*16, q[r], s[r]);
        ushort* p1o = (ushort*)s_p1h + img*(P1_IMGU*2) + c*(P1_CHU*2) + pw;
        #pragma unroll
        for (int ph=0; ph<14; ph++) {
            ld_row(xim + (2*ph+4)*16, q[(2*ph+4)%6], s[(2*ph+4)%6]);
            ld_row(xim + (2*ph+5)*16, q[(2*ph+5)%6], s[(2*ph+5)%6]);
            float sum = 0.f;
            #pragma unroll
            for (int dy=0; dy<2; dy++)
            #pragma unroll
            for (int dx=0; dx<2; dx++) {
                float t = bias;
                #pragma unroll
                for (int ky=0; ky<5; ky++) {
                    const int sl = (2*ph+dy+ky)%6;
                    const uint* rr = dx ? s[sl] : q[sl];
                    t = fdot2(rr[0], wp[ky][0], t);
                    t = fdot2(rr[1], wp[ky][1], t);
                    t = fdot2(rr[2], wp[ky][2], t);
                }
                sum += fast_tanh(t);
            }
            p1o[ph*14] = f16rn(0.25f*sum);
        }
    }
    __syncthreads();

    // ---- stage 3: grouped C3 + tanh + 2x2 avgpool -> p2 fp16 in s_u ----
    for (int idx=tid; idx<IMGS*80; idx+=THREADS) {
        const int o = idx/40, r2 = idx%40, img = r2/5, pw = r2%5;
        const int ncin = g3_ncin(o);
        const float bias = s_w[O_GB + g3_bi(o)];
        float acc0[10], acc1[10];
        #pragma unroll
        for (int h=0;h<10;h++){ acc0[h]=bias; acc1[h]=bias; }
        for (int j=0;j<ncin;j++) {
            const uint* p1c = s_p1h + img*P1_IMGU + g3_ch(o,j)*P1_CHU + pw;
            uint wp[5][3];
            const int slot = g3_slot(o,j);
            #pragma unroll
            for (int k=0;k<15;k++) ((uint*)wp)[k] = s_whu[slot*16 + k];
            #pragma unroll
            for (int r=0;r<14;r++) {
                uint a = p1c[r*7], b = p1c[r*7+1], cc = p1c[r*7+2];
                uint s0 = (b << 16) | (a >> 16);
                uint s1 = (cc << 16) | (b >> 16);
                uint s2 = cc >> 16;
                #pragma unroll
                for (int ky=0;ky<5;ky++) {
                    const int hh = r - ky;
                    if (hh >= 0 && hh < 10) {
                        acc0[hh] = fdot2(cc, wp[ky][2], fdot2(b,  wp[ky][1], fdot2(a,  wp[ky][0], acc0[hh])));
                        acc1[hh] = fdot2(s2, wp[ky][2], fdot2(s1, wp[ky][1], fdot2(s0, wp[ky][0], acc1[hh])));
                    }
                }
            }
        }
        ushort* p2o = (ushort*)s_u + img*(P2_IMGU*2) + o*25 + pw;
        #pragma unroll
        for (int ph=0; ph<5; ph++) {
            float t = fast_tanh(acc0[2*ph])   + fast_tanh(acc1[2*ph])
                    + fast_tanh(acc0[2*ph+1]) + fast_tanh(acc1[2*ph+1]);
            p2o[ph*5] = f16rn(0.25f*t);
        }
    }
    __syncthreads();

    // ---- stage 4: conv5 = 120x400 matvec + tanh -> c5 fp16 ----
    // img = tid>>5: 32 lanes share one img -> LDS reads broadcast
    {
        const int img = tid >> 5, fl = tid & 31;
        const uint* pr = s_u + img * P2_IMGU;
        #pragma unroll
        for (int it=0; it<4; it++) {
            const int f = fl + 32*it;
            if (f < 120) {
                float a0=0.f, a1=0.f;
                if constexpr (H) {
                    const uint2* wr = (const uint2*)(wsh + f*400);
                    #pragma unroll 4
                    for (int k=0;k<100;k++) {          // 100 x uint2 = 400 halves
                        uint2 w2 = wr[k];
                        a0 = fdot2(pr[2*k],   w2.x, a0);
                        a1 = fdot2(pr[2*k+1], w2.y, a1);
                    }
                } else {
                    const float4* wr = (const float4*)(c5_w + f*400);
                    #pragma unroll 4
                    for (int k=0;k<100;k++) {          // 100 x float4 = 400 floats
                        float4 w4 = wr[k];
                        h2 h0 = __builtin_bit_cast(h2, pr[2*k]);
                        h2 h1 = __builtin_bit_cast(h2, pr[2*k+1]);
                        a0 = fmaf((float)h0.x, w4.x, a0);
                        a0 = fmaf((float)h0.y, w4.y, a0);
                        a1 = fmaf((float)h1.x, w4.z, a1);
                        a1 = fmaf((float)h1.y, w4.w, a1);
                    }
                }
                ((ushort*)s_c5u)[img*(C5_IMGU*2) + f] =
                    f16rn(fast_tanh(a0 + a1 + s_w[O_C5B + f]));
            }
        }
    }
    __syncthreads();

    // ---- stage 5: f6 (84x120) + tanh -> s_f6 fp32 (aliases dead p1) ----
    {
        const int img = tid >> 5, jl = tid & 31;
        const uint* cr = s_c5u + img * C5_IMGU;
        #pragma unroll
        for (int it=0; it<3; it++) {
            const int j = jl + 32*it;
            if (j < 84) {
                float a0=0.f, a1=0.f;
                if constexpr (H) {
                    const uint2* wr = (const uint2*)(wsh + 48000 + j*120);
                    #pragma unroll
                    for (int k=0;k<30;k++) {           // 30 x uint2 = 120 halves
                        uint2 w2 = wr[k];
                        a0 = fdot2(cr[2*k],   w2.x, a0);
                        a1 = fdot2(cr[2*k+1], w2.y, a1);
                    }
                } else {
                    const float2* wr = (const float2*)(f6_w + j*120);
                    #pragma unroll
                    for (int k=0;k<60;k++) {           // 60 x float2 = 120 floats
                        float2 w2 = wr[k];
                        h2 hp = __builtin_bit_cast(h2, cr[k]);
                        a0 = fmaf((float)hp.x, w2.x, a0);
                        a1 = fmaf((float)hp.y, w2.y, a1);
                    }
                }
                s_f6[img*84 + j] = fast_tanh(a0 + a1 + s_w[O_F6B + j]);
            }
        }
    }
    __syncthreads();

    // ---- stage 6: out (10x84) -> global ----
    if (tid < 80) {
        const int j = tid >> 3, img = tid & 7;
        const float* wr = out_w + j*84;
        const float* fr = s_f6 + img*84;
        float a0=0.f,a1=0.f,a2=0.f,a3=0.f;
        #pragma unroll
        for (int k=0;k<84;k+=4) {
            a0=fmaf(wr[k],  fr[k],  a0); a1=fmaf(wr[k+1],fr[k+1],a1);
            a2=fmaf(wr[k+2],fr[k+2],a2); a3=fmaf(wr[k+3],fr[k+3],a3);
        }
        out[((size_t)blk*IMGS + img)*10 + j] = (a0+a1)+(a2+a3) + out_b[j];
    }
}

extern "C" void kernel_launch(void* const* d_in, const int* in_sizes, int n_in,
                              void* d_out, int out_size, void* d_ws, size_t ws_size,
                              hipStream_t stream) {
    const float* x    = (const float*)d_in[0];
    const float* c1w  = (const float*)d_in[1];
    const float* c1b  = (const float*)d_in[2];
    const float* fsw  = (const float*)d_in[3];
    const float* fsb  = (const float*)d_in[4];
    const float* scw  = (const float*)d_in[5];
    const float* scb  = (const float*)d_in[6];
    const float* thw  = (const float*)d_in[7];
    const float* thb  = (const float*)d_in[8];
    const float* fow  = (const float*)d_in[9];
    const float* fob  = (const float*)d_in[10];
    const float* c5w  = (const float*)d_in[11];
    const float* c5b  = (const float*)d_in[12];
    const float* f6w  = (const float*)d_in[13];
    const float* f6b  = (const float*)d_in[14];
    const float* outw = (const float*)d_in[15];
    const float* outb = (const float*)d_in[16];
    float* outp = (float*)d_out;

    const int B = in_sizes[0] / 1024;     // 16384
    const int nblk = B / IMGS;            // 2048
    const size_t ws_need = (48000 + 10080) * sizeof(ushort);

    if (ws_size >= ws_need) {
        ushort* wsh = (ushort*)d_ws;
        cvt_w16<<<188, 256, 0, stream>>>(c5w, f6w, wsh);
        lenet_fused<true><<<nblk, THREADS, 0, stream>>>(
            x, c1w, c1b, fsw, fsb, scw, scb, thw, thb, fow, fob,
            c5w, c5b, f6w, f6b, outw, outb, wsh, outp);
    } else {
        lenet_fused<false><<<nblk, THREADS, 0, stream>>>(
            x, c1w, c1b, fsw, fsb, scw, scb, thw, thb, fow, fob,
            c5w, c5b, f6w, f6b, outw, outb, (const ushort*)nullptr, outp);
    }
}

// Round 7
// 204.551 us; speedup vs baseline: 2.5652x; 1.0646x over previous
//
#include <hip/hip_runtime.h>

#define THREADS 256
#define IMGS 4

// fp32 bias offsets in s_w
#define O_C1B 0
#define O_GB  6
#define O_C5B 10
#define O_F6B 130
#define SW_SIZE 214

// p1 fp16 layout (uint units): ch stride mod32=9, img stride mod32=22 -> full bank spread
#define P1_CHU 105
#define P1_IMGU 630
// p2 fp16: 201 uints/img (402 halves, 400 used), mod32=9
#define P2_IMGU 201
// c5 fp16: 61 uints/img (122 halves, 120 used), mod32=29
#define C5_IMGU 61

typedef _Float16 h2 __attribute__((ext_vector_type(2)));

__device__ __forceinline__ float fdot2(uint a, uint b, float c) {
    return __builtin_amdgcn_fdot2(__builtin_bit_cast(h2, a), __builtin_bit_cast(h2, b), c, false);
}
__device__ __forceinline__ uint pkh2(float a, float b) {
    return __builtin_bit_cast(uint, __builtin_amdgcn_cvt_pkrtz(a, b));
}
__device__ __forceinline__ ushort f16rn(float a) {
    _Float16 h = (_Float16)a;
    return __builtin_bit_cast(ushort, h);
}

__device__ __forceinline__ float fast_tanh(float v) {
    float e = __expf(2.f * v);
    return 1.f - __fdividef(2.f, e + 1.f);
}

// load one 6-half row: q = aligned pairs, s = shifted-by-1 pairs
__device__ __forceinline__ void ld_row(const uint* p, uint* q, uint* s) {
    uint a = p[0], b = p[1], c = p[2];
    q[0] = a; q[1] = b; q[2] = c;
    s[0] = (b << 16) | (a >> 16);
    s[1] = (c << 16) | (b >> 16);
    s[2] = c >> 16;
}

// grouped-C3 tables
__device__ __forceinline__ int g3_ncin(int o){ return o<6?3:(o<15?4:6); }
__device__ __forceinline__ int g3_slot(int o,int j){
    return o<6 ? 6+j : (o<12 ? 9+j : (o<15 ? 13+j : 17+j));
}
__device__ __forceinline__ int g3_bi(int o){ return o<6?0:(o<12?1:(o<15?2:3)); }
__device__ __forceinline__ int g3_ch(int o,int j){
    if (o<6)  return (o+j)%6;
    if (o<12) return (o-6+j)%6;
    if (o<15) return (o-12 + j + (j>=2?1:0))%6;
    return j;
}

// pre-kernel: convert c5_w / f6_w to fp16 in workspace (RN)
__global__ __launch_bounds__(256)
void cvt_w16(const float* __restrict__ c5w, const float* __restrict__ f6w,
             ushort* __restrict__ ws) {
    int i = blockIdx.x * 256 + threadIdx.x;
    if (i < 48000) ws[i] = f16rn(c5w[i]);
    if (i < 10080) ws[48000 + i] = f16rn(f6w[i]);
}

template<bool H>
__global__ __launch_bounds__(THREADS)
void lenet_fused(const float* __restrict__ x,
                 const float* __restrict__ c1_w, const float* __restrict__ c1_b,
                 const float* __restrict__ fs_w, const float* __restrict__ fs_b,
                 const float* __restrict__ sc_w, const float* __restrict__ sc_b,
                 const float* __restrict__ th_w, const float* __restrict__ th_b,
                 const float* __restrict__ fo_w, const float* __restrict__ fo_b,
                 const float* __restrict__ c5_w, const float* __restrict__ c5_b,
                 const float* __restrict__ f6_w, const float* __restrict__ f6_b,
                 const float* __restrict__ out_w, const float* __restrict__ out_b,
                 const ushort* __restrict__ wsh,
                 float* __restrict__ out)
{
    __shared__ uint  s_p1h[IMGS * P1_IMGU];   // 10080 B; f6 (fp32) aliases after stage 4
    __shared__ uint  s_whu[23 * 16];          // 1472 B packed fp16 conv weights (row-padded)
    __shared__ float s_w[SW_SIZE];            // 856 B fp32 biases
    __shared__ uint  s_u[IMGS * 512];         // 8192 B union:
                                              //  stages 1-2: x fp16 (2048 uints)
                                              //  stages 3-5: p2h [0..803], c5h [804..1047]
    uint*  s_xh  = s_u;
    uint*  s_c5u = s_u + IMGS * P2_IMGU;
    float* s_f6  = (float*)s_p1h;

    const int tid = threadIdx.x;
    const int blk = blockIdx.x;

    // ---- stage 0a: fp32 biases -> LDS ----
    if (tid < 6)  s_w[O_C1B + tid] = c1_b[tid];
    if (tid == 0){ s_w[O_GB+0]=fs_b[0]; s_w[O_GB+1]=sc_b[0]; s_w[O_GB+2]=th_b[0]; s_w[O_GB+3]=fo_b[0]; }
    if (tid < 120) s_w[O_C5B + tid] = c5_b[tid];
    if (tid < 84)  s_w[O_F6B + tid] = f6_b[tid];

    // ---- stage 0b: conv weights -> packed fp16, row-padded (slot = 16 uints) ----
    if (tid < 23) {
        const float* src;
        if      (tid < 6)  src = c1_w + tid*25;
        else if (tid < 9)  src = fs_w + (tid-6)*25;
        else if (tid < 13) src = sc_w + (tid-9)*25;
        else if (tid < 17) src = th_w + (tid-13)*25;
        else               src = fo_w + (tid-17)*25;
        uint* dst = s_whu + tid*16;
        #pragma unroll
        for (int ky=0; ky<5; ky++) {
            dst[ky*3+0] = pkh2(src[ky*5+0], src[ky*5+1]);
            dst[ky*3+1] = pkh2(src[ky*5+2], src[ky*5+3]);
            dst[ky*3+2] = pkh2(src[ky*5+4], 0.f);
        }
    }

    // ---- stage 1: x -> LDS as fp16 pairs ----
    {
        const float4* xg = (const float4*)(x + (size_t)blk*(IMGS*1024));
        uint2* sx = (uint2*)s_u;
        #pragma unroll
        for (int i=0;i<(IMGS*1024/4)/THREADS;i++) {
            float4 v = xg[tid + i*THREADS];
            sx[tid + i*THREADS] = make_uint2(pkh2(v.x,v.y), pkh2(v.z,v.w));
        }
    }
    __syncthreads();

    // ---- stage 2: conv1 + tanh + 2x2 avgpool -> s_p1h (fp16) ----
    for (int idx=tid; idx<IMGS*84; idx+=THREADS) {
        const int img = idx/84, r2 = idx%84, c = r2/14, pw = r2%14;
        const uint* xim = s_xh + img*512 + pw;
        uint wp[5][3];
        #pragma unroll
        for (int k=0;k<15;k++) ((uint*)wp)[k] = s_whu[c*16 + k];
        const float bias = s_w[O_C1B + c];
        uint q[6][3], s[6][3];
        #pragma unroll
        for (int r=0;r<4;r++) ld_row(xim + r*16, q[r], s[r]);
        ushort* p1o = (ushort*)s_p1h + img*(P1_IMGU*2) + c*(P1_CHU*2) + pw;
        #pragma unroll
        for (int ph=0; ph<14; ph++) {
            ld_row(xim + (2*ph+4)*16, q[(2*ph+4)%6], s[(2*ph+4)%6]);
            ld_row(xim + (2*ph+5)*16, q[(2*ph+5)%6], s[(2*ph+5)%6]);
            float sum = 0.f;
            #pragma unroll
            for (int dy=0; dy<2; dy++)
            #pragma unroll
            for (int dx=0; dx<2; dx++) {
                float t = bias;
                #pragma unroll
                for (int ky=0; ky<5; ky++) {
                    const int sl = (2*ph+dy+ky)%6;
                    const uint* rr = dx ? s[sl] : q[sl];
                    t = fdot2(rr[0], wp[ky][0], t);
                    t = fdot2(rr[1], wp[ky][1], t);
                    t = fdot2(rr[2], wp[ky][2], t);
                }
                sum += fast_tanh(t);
            }
            p1o[ph*14] = f16rn(0.25f*sum);
        }
    }
    __syncthreads();

    // ---- stage 3: grouped C3 + tanh + 2x2 avgpool -> p2 fp16 in s_u ----
    for (int idx=tid; idx<IMGS*80; idx+=THREADS) {
        const int o = idx/(IMGS*5), r2 = idx%(IMGS*5), img = r2/5, pw = r2%5;
        const int ncin = g3_ncin(o);
        const float bias = s_w[O_GB + g3_bi(o)];
        float acc0[10], acc1[10];
        #pragma unroll
        for (int h=0;h<10;h++){ acc0[h]=bias; acc1[h]=bias; }
        for (int j=0;j<ncin;j++) {
            const uint* p1c = s_p1h + img*P1_IMGU + g3_ch(o,j)*P1_CHU + pw;
            uint wp[5][3];
            const int slot = g3_slot(o,j);
            #pragma unroll
            for (int k=0;k<15;k++) ((uint*)wp)[k] = s_whu[slot*16 + k];
            #pragma unroll
            for (int r=0;r<14;r++) {
                uint a = p1c[r*7], b = p1c[r*7+1], cc = p1c[r*7+2];
                uint s0 = (b << 16) | (a >> 16);
                uint s1 = (cc << 16) | (b >> 16);
                uint s2 = cc >> 16;
                #pragma unroll
                for (int ky=0;ky<5;ky++) {
                    const int hh = r - ky;
                    if (hh >= 0 && hh < 10) {
                        acc0[hh] = fdot2(cc, wp[ky][2], fdot2(b,  wp[ky][1], fdot2(a,  wp[ky][0], acc0[hh])));
                        acc1[hh] = fdot2(s2, wp[ky][2], fdot2(s1, wp[ky][1], fdot2(s0, wp[ky][0], acc1[hh])));
                    }
                }
            }
        }
        ushort* p2o = (ushort*)s_u + img*(P2_IMGU*2) + o*25 + pw;
        #pragma unroll
        for (int ph=0; ph<5; ph++) {
            float t = fast_tanh(acc0[2*ph])   + fast_tanh(acc1[2*ph])
                    + fast_tanh(acc0[2*ph+1]) + fast_tanh(acc1[2*ph+1]);
            p2o[ph*5] = f16rn(0.25f*t);
        }
    }
    __syncthreads();

    // ---- stage 4: conv5 = 120x400 matvec + tanh -> c5 fp16 ----
    // 4 lanes share one weight row (f = idx>>2), img = idx&3 -> LDS banks spread
    #pragma unroll
    for (int it=0; it<2; it++) {
        const int id2 = tid + THREADS*it;
        if (id2 < 120*IMGS) {
            const int f = id2 >> 2, img = id2 & 3;
            const uint* pr = s_u + img * P2_IMGU;
            float a0=0.f, a1=0.f;
            if constexpr (H) {
                const uint2* wr = (const uint2*)(wsh + f*400);
                #pragma unroll 4
                for (int k=0;k<100;k++) {          // 100 x uint2 = 400 halves
                    uint2 w2 = wr[k];
                    a0 = fdot2(pr[2*k],   w2.x, a0);
                    a1 = fdot2(pr[2*k+1], w2.y, a1);
                }
            } else {
                const float4* wr = (const float4*)(c5_w + f*400);
                #pragma unroll 4
                for (int k=0;k<100;k++) {          // 100 x float4 = 400 floats
                    float4 w4 = wr[k];
                    h2 h0 = __builtin_bit_cast(h2, pr[2*k]);
                    h2 h1 = __builtin_bit_cast(h2, pr[2*k+1]);
                    a0 = fmaf((float)h0.x, w4.x, a0);
                    a0 = fmaf((float)h0.y, w4.y, a0);
                    a1 = fmaf((float)h1.x, w4.z, a1);
                    a1 = fmaf((float)h1.y, w4.w, a1);
                }
            }
            ((ushort*)s_c5u)[img*(C5_IMGU*2) + f] =
                f16rn(fast_tanh(a0 + a1 + s_w[O_C5B + f]));
        }
    }
    __syncthreads();

    // ---- stage 5: f6 (84x120) + tanh -> s_f6 fp32 (aliases dead p1) ----
    #pragma unroll
    for (int it=0; it<2; it++) {
        const int id2 = tid + THREADS*it;
        if (id2 < 84*IMGS) {
            const int j = id2 >> 2, img = id2 & 3;
            const uint* cr = s_c5u + img * C5_IMGU;
            float a0=0.f, a1=0.f;
            if constexpr (H) {
                const uint2* wr = (const uint2*)(wsh + 48000 + j*120);
                #pragma unroll
                for (int k=0;k<30;k++) {           // 30 x uint2 = 120 halves
                    uint2 w2 = wr[k];
                    a0 = fdot2(cr[2*k],   w2.x, a0);
                    a1 = fdot2(cr[2*k+1], w2.y, a1);
                }
            } else {
                const float2* wr = (const float2*)(f6_w + j*120);
                #pragma unroll
                for (int k=0;k<60;k++) {           // 60 x float2 = 120 floats
                    float2 w2 = wr[k];
                    h2 hp = __builtin_bit_cast(h2, cr[k]);
                    a0 = fmaf((float)hp.x, w2.x, a0);
                    a1 = fmaf((float)hp.y, w2.y, a1);
                }
            }
            s_f6[img*84 + j] = fast_tanh(a0 + a1 + s_w[O_F6B + j]);
        }
    }
    __syncthreads();

    // ---- stage 6: out (10x84) -> global ----
    if (tid < 10*IMGS) {
        const int j = tid >> 2, img = tid & 3;
        const float* wr = out_w + j*84;
        const float* fr = s_f6 + img*84;
        float a0=0.f,a1=0.f,a2=0.f,a3=0.f;
        #pragma unroll
        for (int k=0;k<84;k+=4) {
            a0=fmaf(wr[k],  fr[k],  a0); a1=fmaf(wr[k+1],fr[k+1],a1);
            a2=fmaf(wr[k+2],fr[k+2],a2); a3=fmaf(wr[k+3],fr[k+3],a3);
        }
        out[((size_t)blk*IMGS + img)*10 + j] = (a0+a1)+(a2+a3) + out_b[j];
    }
}

extern "C" void kernel_launch(void* const* d_in, const int* in_sizes, int n_in,
                              void* d_out, int out_size, void* d_ws, size_t ws_size,
                              hipStream_t stream) {
    const float* x    = (const float*)d_in[0];
    const float* c1w  = (const float*)d_in[1];
    const float* c1b  = (const float*)d_in[2];
    const float* fsw  = (const float*)d_in[3];
    const float* fsb  = (const float*)d_in[4];
    const float* scw  = (const float*)d_in[5];
    const float* scb  = (const float*)d_in[6];
    const float* thw  = (const float*)d_in[7];
    const float* thb  = (const float*)d_in[8];
    const float* fow  = (const float*)d_in[9];
    const float* fob  = (const float*)d_in[10];
    const float* c5w  = (const float*)d_in[11];
    const float* c5b  = (const float*)d_in[12];
    const float* f6w  = (const float*)d_in[13];
    const float* f6b  = (const float*)d_in[14];
    const float* outw = (const float*)d_in[15];
    const float* outb = (const float*)d_in[16];
    float* outp = (float*)d_out;

    const int B = in_sizes[0] / 1024;     // 16384
    const int nblk = B / IMGS;            // 4096
    const size_t ws_need = (48000 + 10080) * sizeof(ushort);

    if (ws_size >= ws_need) {
        ushort* wsh = (ushort*)d_ws;
        cvt_w16<<<188, 256, 0, stream>>>(c5w, f6w, wsh);
        lenet_fused<true><<<nblk, THREADS, 0, stream>>>(
            x, c1w, c1b, fsw, fsb, scw, scb, thw, thb, fow, fob,
            c5w, c5b, f6w, f6b, outw, outb, wsh, outp);
    } else {
        lenet_fused<false><<<nblk, THREADS, 0, stream>>>(
            x, c1w, c1b, fsw, fsb, scw, scb, thw, thb, fow, fob,
            c5w, c5b, f6w, f6b, outw, outb, (const ushort*)nullptr, outp);
    }
}

// Round 8
// 201.470 us; speedup vs baseline: 2.6045x; 1.0153x over previous
//
#include <hip/hip_runtime.h>

#define THREADS 256
#define IMGS 4

// s_w (fp32): c1b[0..5], group biases [6..9]
#define O_C1B 0
#define O_GB  6

// p1 fp16 layout (uint units): ch stride mod32=9, img stride mod32=22 -> full bank spread
#define P1_CHU 105
#define P1_IMGU 630
// p2 fp16: 201 uints/img (402 halves, 400 used), mod32=9
#define P2_IMGU 201
// c5 fp16: 61 uints/img (122 halves, 120 used), mod32=29
#define C5_IMGU 61

typedef _Float16 h2 __attribute__((ext_vector_type(2)));

__device__ __forceinline__ float fdot2(uint a, uint b, float c) {
    return __builtin_amdgcn_fdot2(__builtin_bit_cast(h2, a), __builtin_bit_cast(h2, b), c, false);
}
__device__ __forceinline__ uint pkh2(float a, float b) {
    return __builtin_bit_cast(uint, __builtin_amdgcn_cvt_pkrtz(a, b));
}
__device__ __forceinline__ ushort f16rn(float a) {
    _Float16 h = (_Float16)a;
    return __builtin_bit_cast(ushort, h);
}
__device__ __forceinline__ float h2lo(uint w){ return (float)__builtin_bit_cast(h2, w).x; }
__device__ __forceinline__ float h2hi(uint w){ return (float)__builtin_bit_cast(h2, w).y; }

// (hi:lo) >> 16 -> one v_alignbit_b32
__device__ __forceinline__ uint funnel16(uint hi, uint lo) {
    return __builtin_amdgcn_alignbit(hi, lo, 16);
}

__device__ __forceinline__ float fast_tanh(float v) {
    float e = __expf(2.f * v);
    return 1.f - __fdividef(2.f, e + 1.f);
}

// load one 6-half row: q = aligned pairs, s = shifted-by-1 pairs
__device__ __forceinline__ void ld_row(const uint* p, uint* q, uint* s) {
    uint a = p[0], b = p[1], c = p[2];
    q[0] = a; q[1] = b; q[2] = c;
    s[0] = funnel16(b, a);
    s[1] = funnel16(c, b);
    s[2] = c >> 16;
}

// grouped-C3 tables
__device__ __forceinline__ int g3_ncin(int o){ return o<6?3:(o<15?4:6); }
__device__ __forceinline__ int g3_slot(int o,int j){
    return o<6 ? 6+j : (o<12 ? 9+j : (o<15 ? 13+j : 17+j));
}
__device__ __forceinline__ int g3_bi(int o){ return o<6?0:(o<12?1:(o<15?2:3)); }
__device__ __forceinline__ int g3_ch(int o,int j){
    if (o<6)  return (o+j)%6;
    if (o<12) return (o-6+j)%6;
    if (o<15) return (o-12 + j + (j>=2?1:0))%6;
    return j;
}

// pre-kernel: convert c5_w / f6_w to fp16 in workspace (RN)
__global__ __launch_bounds__(256)
void cvt_w16(const float* __restrict__ c5w, const float* __restrict__ f6w,
             ushort* __restrict__ ws) {
    int i = blockIdx.x * 256 + threadIdx.x;
    if (i < 48000) ws[i] = f16rn(c5w[i]);
    if (i < 10080) ws[48000 + i] = f16rn(f6w[i]);
}

template<bool H>
__global__ __launch_bounds__(THREADS, 8)
void lenet_fused(const float* __restrict__ x,
                 const float* __restrict__ c1_w, const float* __restrict__ c1_b,
                 const float* __restrict__ fs_w, const float* __restrict__ fs_b,
                 const float* __restrict__ sc_w, const float* __restrict__ sc_b,
                 const float* __restrict__ th_w, const float* __restrict__ th_b,
                 const float* __restrict__ fo_w, const float* __restrict__ fo_b,
                 const float* __restrict__ c5_w, const float* __restrict__ c5_b,
                 const float* __restrict__ f6_w, const float* __restrict__ f6_b,
                 const float* __restrict__ out_w, const float* __restrict__ out_b,
                 const ushort* __restrict__ wsh,
                 float* __restrict__ out)
{
    __shared__ uint  s_p1h[IMGS * P1_IMGU];   // 10080 B; f6 (fp32) aliases after stage 4
    __shared__ uint  s_whu[23 * 16];          // 1472 B packed fp16 conv weights (row-padded)
    __shared__ float s_w[10];                 // 40 B fp32 biases (c1b, group)
    __shared__ uint  s_bh[102];               // 408 B fp16 biases: c5b [0..59], f6b [60..101]
    __shared__ uint  s_u[IMGS * 512];         // 8192 B union:
                                              //  stages 1-2: x fp16 (2048 uints)
                                              //  stages 3-5: p2h [0..803], c5h [804..1047]
    uint*  s_xh  = s_u;
    uint*  s_c5u = s_u + IMGS * P2_IMGU;
    float* s_f6  = (float*)s_p1h;

    const int tid = threadIdx.x;
    const int blk = blockIdx.x;

    // ---- stage 0a: biases -> LDS ----
    if (tid < 6)  s_w[O_C1B + tid] = c1_b[tid];
    if (tid == 0){ s_w[O_GB+0]=fs_b[0]; s_w[O_GB+1]=sc_b[0]; s_w[O_GB+2]=th_b[0]; s_w[O_GB+3]=fo_b[0]; }
    if (tid < 60) s_bh[tid]      = pkh2(c5_b[2*tid], c5_b[2*tid+1]);
    if (tid < 42) s_bh[60 + tid] = pkh2(f6_b[2*tid], f6_b[2*tid+1]);

    // ---- stage 0b: conv weights -> packed fp16, row-padded (slot = 16 uints) ----
    if (tid < 23) {
        const float* src;
        if      (tid < 6)  src = c1_w + tid*25;
        else if (tid < 9)  src = fs_w + (tid-6)*25;
        else if (tid < 13) src = sc_w + (tid-9)*25;
        else if (tid < 17) src = th_w + (tid-13)*25;
        else               src = fo_w + (tid-17)*25;
        uint* dst = s_whu + tid*16;
        #pragma unroll
        for (int ky=0; ky<5; ky++) {
            dst[ky*3+0] = pkh2(src[ky*5+0], src[ky*5+1]);
            dst[ky*3+1] = pkh2(src[ky*5+2], src[ky*5+3]);
            dst[ky*3+2] = pkh2(src[ky*5+4], 0.f);
        }
    }

    // ---- stage 1: x -> LDS as fp16 pairs ----
    {
        const float4* xg = (const float4*)(x + (size_t)blk*(IMGS*1024));
        uint2* sx = (uint2*)s_u;
        #pragma unroll
        for (int i=0;i<(IMGS*1024/4)/THREADS;i++) {
            float4 v = xg[tid + i*THREADS];
            sx[tid + i*THREADS] = make_uint2(pkh2(v.x,v.y), pkh2(v.z,v.w));
        }
    }
    __syncthreads();

    // ---- stage 2: conv1 + tanh + 2x2 avgpool -> s_p1h (fp16) ----
    for (int idx=tid; idx<IMGS*84; idx+=THREADS) {
        const int img = idx/84, r2 = idx%84, c = r2/14, pw = r2%14;
        const uint* xim = s_xh + img*512 + pw;
        uint wp[5][3];
        #pragma unroll
        for (int k=0;k<15;k++) ((uint*)wp)[k] = s_whu[c*16 + k];
        const float bias = s_w[O_C1B + c];
        uint q[6][3], s[6][3];
        #pragma unroll
        for (int r=0;r<4;r++) ld_row(xim + r*16, q[r], s[r]);
        ushort* p1o = (ushort*)s_p1h + img*(P1_IMGU*2) + c*(P1_CHU*2) + pw;
        #pragma unroll
        for (int ph=0; ph<14; ph++) {
            ld_row(xim + (2*ph+4)*16, q[(2*ph+4)%6], s[(2*ph+4)%6]);
            ld_row(xim + (2*ph+5)*16, q[(2*ph+5)%6], s[(2*ph+5)%6]);
            float sum = 0.f;
            #pragma unroll
            for (int dy=0; dy<2; dy++)
            #pragma unroll
            for (int dx=0; dx<2; dx++) {
                float t = bias;
                #pragma unroll
                for (int ky=0; ky<5; ky++) {
                    const int sl = (2*ph+dy+ky)%6;
                    const uint* rr = dx ? s[sl] : q[sl];
                    t = fdot2(rr[0], wp[ky][0], t);
                    t = fdot2(rr[1], wp[ky][1], t);
                    t = fdot2(rr[2], wp[ky][2], t);
                }
                sum += fast_tanh(t);
            }
            p1o[ph*14] = f16rn(0.25f*sum);
        }
    }
    __syncthreads();

    // ---- stage 3: grouped C3 + tanh + 2x2 avgpool -> p2 fp16 in s_u ----
    for (int idx=tid; idx<IMGS*80; idx+=THREADS) {
        const int o = idx/(IMGS*5), r2 = idx%(IMGS*5), img = r2/5, pw = r2%5;
        const int ncin = g3_ncin(o);
        const float bias = s_w[O_GB + g3_bi(o)];
        float acc0[10], acc1[10];
        #pragma unroll
        for (int h=0;h<10;h++){ acc0[h]=bias; acc1[h]=bias; }
        for (int j=0;j<ncin;j++) {
            const uint* p1c = s_p1h + img*P1_IMGU + g3_ch(o,j)*P1_CHU + pw;
            uint wp[5][3];
            const int slot = g3_slot(o,j);
            #pragma unroll
            for (int k=0;k<15;k++) ((uint*)wp)[k] = s_whu[slot*16 + k];
            #pragma unroll
            for (int r=0;r<14;r++) {
                uint a = p1c[r*7], b = p1c[r*7+1], cc = p1c[r*7+2];
                uint s0 = funnel16(b, a);
                uint s1 = funnel16(cc, b);
                uint s2 = cc >> 16;
                #pragma unroll
                for (int ky=0;ky<5;ky++) {
                    const int hh = r - ky;
                    if (hh >= 0 && hh < 10) {
                        acc0[hh] = fdot2(cc, wp[ky][2], fdot2(b,  wp[ky][1], fdot2(a,  wp[ky][0], acc0[hh])));
                        acc1[hh] = fdot2(s2, wp[ky][2], fdot2(s1, wp[ky][1], fdot2(s0, wp[ky][0], acc1[hh])));
                    }
                }
            }
        }
        ushort* p2o = (ushort*)s_u + img*(P2_IMGU*2) + o*25 + pw;
        #pragma unroll
        for (int ph=0; ph<5; ph++) {
            float t = fast_tanh(acc0[2*ph])   + fast_tanh(acc1[2*ph])
                    + fast_tanh(acc0[2*ph+1]) + fast_tanh(acc1[2*ph+1]);
            p2o[ph*5] = f16rn(0.25f*t);
        }
    }
    __syncthreads();

    // ---- stage 4: conv5 = 120x400 matvec + tanh -> c5 fp16 ----
    #pragma unroll
    for (int it=0; it<2; it++) {
        const int id2 = tid + THREADS*it;
        if (id2 < 120*IMGS) {
            const int f = id2 >> 2, img = id2 & 3;
            const uint* pr = s_u + img * P2_IMGU;
            float a0=0.f, a1=0.f, a2=0.f, a3=0.f;
            if constexpr (H) {
                const uint4* wr = (const uint4*)(wsh + f*400);   // 50 x uint4 = 400 halves
                #pragma unroll 5
                for (int k=0;k<50;k++) {
                    uint4 w4 = wr[k];
                    a0 = fdot2(pr[4*k],   w4.x, a0);
                    a1 = fdot2(pr[4*k+1], w4.y, a1);
                    a2 = fdot2(pr[4*k+2], w4.z, a2);
                    a3 = fdot2(pr[4*k+3], w4.w, a3);
                }
            } else {
                const float4* wr = (const float4*)(c5_w + f*400);
                #pragma unroll 4
                for (int k=0;k<100;k++) {
                    float4 w4 = wr[k];
                    h2 h0 = __builtin_bit_cast(h2, pr[2*k]);
                    h2 h1 = __builtin_bit_cast(h2, pr[2*k+1]);
                    a0 = fmaf((float)h0.x, w4.x, a0);
                    a1 = fmaf((float)h0.y, w4.y, a1);
                    a2 = fmaf((float)h1.x, w4.z, a2);
                    a3 = fmaf((float)h1.y, w4.w, a3);
                }
            }
            const uint bw = s_bh[f >> 1];
            const float bias = (f & 1) ? h2hi(bw) : h2lo(bw);
            ((ushort*)s_c5u)[img*(C5_IMGU*2) + f] =
                f16rn(fast_tanh((a0+a1)+(a2+a3) + bias));
        }
    }
    __syncthreads();

    // ---- stage 5: f6 (84x120) + tanh -> s_f6 fp32 (aliases dead p1) ----
    #pragma unroll
    for (int it=0; it<2; it++) {
        const int id2 = tid + THREADS*it;
        if (id2 < 84*IMGS) {
            const int j = id2 >> 2, img = id2 & 3;
            const uint* cr = s_c5u + img * C5_IMGU;
            float a0=0.f, a1=0.f, a2=0.f, a3=0.f;
            if constexpr (H) {
                const uint4* wr = (const uint4*)(wsh + 48000 + j*120); // 15 x uint4
                #pragma unroll
                for (int k=0;k<15;k++) {
                    uint4 w4 = wr[k];
                    a0 = fdot2(cr[4*k],   w4.x, a0);
                    a1 = fdot2(cr[4*k+1], w4.y, a1);
                    a2 = fdot2(cr[4*k+2], w4.z, a2);
                    a3 = fdot2(cr[4*k+3], w4.w, a3);
                }
            } else {
                const float2* wr = (const float2*)(f6_w + j*120);
                #pragma unroll
                for (int k=0;k<60;k++) {
                    float2 w2 = wr[k];
                    h2 hp = __builtin_bit_cast(h2, cr[k]);
                    a0 = fmaf((float)hp.x, w2.x, a0);
                    a1 = fmaf((float)hp.y, w2.y, a1);
                }
            }
            const uint bw = s_bh[60 + (j >> 1)];
            const float bias = (j & 1) ? h2hi(bw) : h2lo(bw);
            s_f6[img*84 + j] = fast_tanh((a0+a1)+(a2+a3) + bias);
        }
    }
    __syncthreads();

    // ---- stage 6: out (10x84) -> global ----
    if (tid < 10*IMGS) {
        const int j = tid >> 2, img = tid & 3;
        const float* wr = out_w + j*84;
        const float* fr = s_f6 + img*84;
        float a0=0.f,a1=0.f,a2=0.f,a3=0.f;
        #pragma unroll
        for (int k=0;k<84;k+=4) {
            a0=fmaf(wr[k],  fr[k],  a0); a1=fmaf(wr[k+1],fr[k+1],a1);
            a2=fmaf(wr[k+2],fr[k+2],a2); a3=fmaf(wr[k+3],fr[k+3],a3);
        }
        out[((size_t)blk*IMGS + img)*10 + j] = (a0+a1)+(a2+a3) + out_b[j];
    }
}

extern "C" void kernel_launch(void* const* d_in, const int* in_sizes, int n_in,
                              void* d_out, int out_size, void* d_ws, size_t ws_size,
                              hipStream_t stream) {
    const float* x    = (const float*)d_in[0];
    const float* c1w  = (const float*)d_in[1];
    const float* c1b  = (const float*)d_in[2];
    const float* fsw  = (const float*)d_in[3];
    const float* fsb  = (const float*)d_in[4];
    const float* scw  = (const float*)d_in[5];
    const float* scb  = (const float*)d_in[6];
    const float* thw  = (const float*)d_in[7];
    const float* thb  = (const float*)d_in[8];
    const float* fow  = (const float*)d_in[9];
    const float* fob  = (const float*)d_in[10];
    const float* c5w  = (const float*)d_in[11];
    const float* c5b  = (const float*)d_in[12];
    const float* f6w  = (const float*)d_in[13];
    const float* f6b  = (const float*)d_in[14];
    const float* outw = (const float*)d_in[15];
    const float* outb = (const float*)d_in[16];
    float* outp = (float*)d_out;

    const int B = in_sizes[0] / 1024;     // 16384
    const int nblk = B / IMGS;            // 4096
    const size_t ws_need = (48000 + 10080) * sizeof(ushort);

    if (ws_size >= ws_need) {
        ushort* wsh = (ushort*)d_ws;
        cvt_w16<<<188, 256, 0, stream>>>(c5w, f6w, wsh);
        lenet_fused<true><<<nblk, THREADS, 0, stream>>>(
            x, c1w, c1b, fsw, fsb, scw, scb, thw, thb, fow, fob,
            c5w, c5b, f6w, f6b, outw, outb, wsh, outp);
    } else {
        lenet_fused<false><<<nblk, THREADS, 0, stream>>>(
            x, c1w, c1b, fsw, fsb, scw, scb, thw, thb, fow, fob,
            c5w, c5b, f6w, f6b, outw, outb, (const ushort*)nullptr, outp);
    }
}

// Round 9
// 201.386 us; speedup vs baseline: 2.6055x; 1.0004x over previous
//
#include <hip/hip_runtime.h>

#define THREADS 256
#define IMGS 4

// s_w (fp32): c1b[0..5], group biases [6..9]
#define O_C1B 0
#define O_GB  6

// p1 fp16 layout (uint units): ch stride mod32=9, img stride mod32=22 -> full bank spread
#define P1_CHU 105
#define P1_IMGU 630
// p2 fp16: 201 uints/img (402 halves, 400 used), mod32=9
#define P2_IMGU 201
// c5 fp16: 61 uints/img (122 halves, 120 used), mod32=29
#define C5_IMGU 61

typedef _Float16 h2 __attribute__((ext_vector_type(2)));

__device__ __forceinline__ float fdot2(uint a, uint b, float c) {
    return __builtin_amdgcn_fdot2(__builtin_bit_cast(h2, a), __builtin_bit_cast(h2, b), c, false);
}
__device__ __forceinline__ uint pkh2(float a, float b) {
    return __builtin_bit_cast(uint, __builtin_amdgcn_cvt_pkrtz(a, b));
}
__device__ __forceinline__ ushort f16rn(float a) {
    _Float16 h = (_Float16)a;
    return __builtin_bit_cast(ushort, h);
}
__device__ __forceinline__ float h2lo(uint w){ return (float)__builtin_bit_cast(h2, w).x; }
__device__ __forceinline__ float h2hi(uint w){ return (float)__builtin_bit_cast(h2, w).y; }

// (hi:lo) >> 16 -> one v_alignbit_b32
__device__ __forceinline__ uint funnel16(uint hi, uint lo) {
    return __builtin_amdgcn_alignbit(hi, lo, 16);
}

__device__ __forceinline__ float fast_tanh(float v) {
    float e = __expf(2.f * v);
    return 1.f - __fdividef(2.f, e + 1.f);
}

// load one 6-half row: q = aligned pairs, s = shifted-by-1 pairs
__device__ __forceinline__ void ld_row(const uint* p, uint* q, uint* s) {
    uint a = p[0], b = p[1], c = p[2];
    q[0] = a; q[1] = b; q[2] = c;
    s[0] = funnel16(b, a);
    s[1] = funnel16(c, b);
    s[2] = c >> 16;
}

// grouped-C3 tables
__device__ __forceinline__ int g3_ncin(int o){ return o<6?3:(o<15?4:6); }
__device__ __forceinline__ int g3_slot(int o,int j){
    return o<6 ? 6+j : (o<12 ? 9+j : (o<15 ? 13+j : 17+j));
}
__device__ __forceinline__ int g3_bi(int o){ return o<6?0:(o<12?1:(o<15?2:3)); }
__device__ __forceinline__ int g3_ch(int o,int j){
    if (o<6)  return (o+j)%6;
    if (o<12) return (o-6+j)%6;
    if (o<15) return (o-12 + j + (j>=2?1:0))%6;
    return j;
}

// pre-kernel: convert c5_w / f6_w to fp16 in workspace (RN)
__global__ __launch_bounds__(256)
void cvt_w16(const float* __restrict__ c5w, const float* __restrict__ f6w,
             ushort* __restrict__ ws) {
    int i = blockIdx.x * 256 + threadIdx.x;
    if (i < 48000) ws[i] = f16rn(c5w[i]);
    if (i < 10080) ws[48000 + i] = f16rn(f6w[i]);
}

template<bool H>
__global__ __launch_bounds__(THREADS)
void lenet_fused(const float* __restrict__ x,
                 const float* __restrict__ c1_w, const float* __restrict__ c1_b,
                 const float* __restrict__ fs_w, const float* __restrict__ fs_b,
                 const float* __restrict__ sc_w, const float* __restrict__ sc_b,
                 const float* __restrict__ th_w, const float* __restrict__ th_b,
                 const float* __restrict__ fo_w, const float* __restrict__ fo_b,
                 const float* __restrict__ c5_w, const float* __restrict__ c5_b,
                 const float* __restrict__ f6_w, const float* __restrict__ f6_b,
                 const float* __restrict__ out_w, const float* __restrict__ out_b,
                 const ushort* __restrict__ wsh,
                 float* __restrict__ out)
{
    __shared__ uint  s_p1h[IMGS * P1_IMGU];   // 10080 B; f6 (fp32) aliases after stage 4
    __shared__ uint  s_whu[23 * 16];          // 1472 B packed fp16 conv weights (row-padded)
    __shared__ float s_w[10];                 // 40 B fp32 biases (c1b, group)
    __shared__ uint  s_bh[102];               // 408 B fp16 biases: c5b [0..59], f6b [60..101]
    __shared__ uint  s_u[IMGS * 512];         // 8192 B union:
                                              //  stages 1-2: x fp16 (2048 uints)
                                              //  stages 3-5: p2h [0..803], c5h [804..1047]
    uint*  s_xh  = s_u;
    uint*  s_c5u = s_u + IMGS * P2_IMGU;
    float* s_f6  = (float*)s_p1h;

    const int tid = threadIdx.x;
    const int blk = blockIdx.x;

    // ---- stage 0a: biases -> LDS ----
    if (tid < 6)  s_w[O_C1B + tid] = c1_b[tid];
    if (tid == 0){ s_w[O_GB+0]=fs_b[0]; s_w[O_GB+1]=sc_b[0]; s_w[O_GB+2]=th_b[0]; s_w[O_GB+3]=fo_b[0]; }
    if (tid < 60) s_bh[tid]      = pkh2(c5_b[2*tid], c5_b[2*tid+1]);
    if (tid < 42) s_bh[60 + tid] = pkh2(f6_b[2*tid], f6_b[2*tid+1]);

    // ---- stage 0b: conv weights -> packed fp16, row-padded (slot = 16 uints) ----
    if (tid < 23) {
        const float* src;
        if      (tid < 6)  src = c1_w + tid*25;
        else if (tid < 9)  src = fs_w + (tid-6)*25;
        else if (tid < 13) src = sc_w + (tid-9)*25;
        else if (tid < 17) src = th_w + (tid-13)*25;
        else               src = fo_w + (tid-17)*25;
        uint* dst = s_whu + tid*16;
        #pragma unroll
        for (int ky=0; ky<5; ky++) {
            dst[ky*3+0] = pkh2(src[ky*5+0], src[ky*5+1]);
            dst[ky*3+1] = pkh2(src[ky*5+2], src[ky*5+3]);
            dst[ky*3+2] = pkh2(src[ky*5+4], 0.f);
        }
    }

    // ---- stage 1: x -> LDS as fp16 pairs ----
    {
        const float4* xg = (const float4*)(x + (size_t)blk*(IMGS*1024));
        uint2* sx = (uint2*)s_u;
        #pragma unroll
        for (int i=0;i<(IMGS*1024/4)/THREADS;i++) {
            float4 v = xg[tid + i*THREADS];
            sx[tid + i*THREADS] = make_uint2(pkh2(v.x,v.y), pkh2(v.z,v.w));
        }
    }
    __syncthreads();

    // ---- stage 2: conv1 + tanh + 2x2 avgpool -> s_p1h (fp16) ----
    for (int idx=tid; idx<IMGS*84; idx+=THREADS) {
        const int img = idx/84, r2 = idx%84, c = r2/14, pw = r2%14;
        const uint* xim = s_xh + img*512 + pw;
        uint wp[5][3];
        #pragma unroll
        for (int k=0;k<15;k++) ((uint*)wp)[k] = s_whu[c*16 + k];
        const float bias = s_w[O_C1B + c];
        uint q[6][3], s[6][3];
        #pragma unroll
        for (int r=0;r<4;r++) ld_row(xim + r*16, q[r], s[r]);
        ushort* p1o = (ushort*)s_p1h + img*(P1_IMGU*2) + c*(P1_CHU*2) + pw;
        #pragma unroll
        for (int ph=0; ph<14; ph++) {
            ld_row(xim + (2*ph+4)*16, q[(2*ph+4)%6], s[(2*ph+4)%6]);
            ld_row(xim + (2*ph+5)*16, q[(2*ph+5)%6], s[(2*ph+5)%6]);
            float sum = 0.f;
            #pragma unroll
            for (int dy=0; dy<2; dy++)
            #pragma unroll
            for (int dx=0; dx<2; dx++) {
                float t = bias;
                #pragma unroll
                for (int ky=0; ky<5; ky++) {
                    const int sl = (2*ph+dy+ky)%6;
                    const uint* rr = dx ? s[sl] : q[sl];
                    t = fdot2(rr[0], wp[ky][0], t);
                    t = fdot2(rr[1], wp[ky][1], t);
                    t = fdot2(rr[2], wp[ky][2], t);
                }
                sum += fast_tanh(t);
            }
            p1o[ph*14] = f16rn(0.25f*sum);
        }
    }
    __syncthreads();

    // ---- stage 3: grouped C3 + tanh + 2x2 avgpool -> p2 fp16 in s_u ----
    for (int idx=tid; idx<IMGS*80; idx+=THREADS) {
        const int o = idx/(IMGS*5), r2 = idx%(IMGS*5), img = r2/5, pw = r2%5;
        const int ncin = g3_ncin(o);
        const float bias = s_w[O_GB + g3_bi(o)];
        float acc0[10], acc1[10];
        #pragma unroll
        for (int h=0;h<10;h++){ acc0[h]=bias; acc1[h]=bias; }
        for (int j=0;j<ncin;j++) {
            const uint* p1c = s_p1h + img*P1_IMGU + g3_ch(o,j)*P1_CHU + pw;
            uint wp[5][3];
            const int slot = g3_slot(o,j);
            #pragma unroll
            for (int k=0;k<15;k++) ((uint*)wp)[k] = s_whu[slot*16 + k];
            #pragma unroll
            for (int r=0;r<14;r++) {
                uint a = p1c[r*7], b = p1c[r*7+1], cc = p1c[r*7+2];
                uint s0 = funnel16(b, a);
                uint s1 = funnel16(cc, b);
                uint s2 = cc >> 16;
                #pragma unroll
                for (int ky=0;ky<5;ky++) {
                    const int hh = r - ky;
                    if (hh >= 0 && hh < 10) {
                        acc0[hh] = fdot2(cc, wp[ky][2], fdot2(b,  wp[ky][1], fdot2(a,  wp[ky][0], acc0[hh])));
                        acc1[hh] = fdot2(s2, wp[ky][2], fdot2(s1, wp[ky][1], fdot2(s0, wp[ky][0], acc1[hh])));
                    }
                }
            }
        }
        ushort* p2o = (ushort*)s_u + img*(P2_IMGU*2) + o*25 + pw;
        #pragma unroll
        for (int ph=0; ph<5; ph++) {
            float t = fast_tanh(acc0[2*ph])   + fast_tanh(acc1[2*ph])
                    + fast_tanh(acc0[2*ph+1]) + fast_tanh(acc1[2*ph+1]);
            p2o[ph*5] = f16rn(0.25f*t);
        }
    }
    __syncthreads();

    // ---- stage 4: conv5 = 120x400 matvec + tanh -> c5 fp16 ----
    #pragma unroll
    for (int it=0; it<2; it++) {
        const int id2 = tid + THREADS*it;
        if (id2 < 120*IMGS) {
            const int f = id2 >> 2, img = id2 & 3;
            const uint* pr = s_u + img * P2_IMGU;
            float a0=0.f, a1=0.f, a2=0.f, a3=0.f;
            if constexpr (H) {
                const uint4* wr = (const uint4*)(wsh + f*400);   // 50 x uint4 = 400 halves
                #pragma unroll 5
                for (int k=0;k<50;k++) {
                    uint4 w4 = wr[k];
                    a0 = fdot2(pr[4*k],   w4.x, a0);
                    a1 = fdot2(pr[4*k+1], w4.y, a1);
                    a2 = fdot2(pr[4*k+2], w4.z, a2);
                    a3 = fdot2(pr[4*k+3], w4.w, a3);
                }
            } else {
                const float4* wr = (const float4*)(c5_w + f*400);
                #pragma unroll 4
                for (int k=0;k<100;k++) {
                    float4 w4 = wr[k];
                    h2 h0 = __builtin_bit_cast(h2, pr[2*k]);
                    h2 h1 = __builtin_bit_cast(h2, pr[2*k+1]);
                    a0 = fmaf((float)h0.x, w4.x, a0);
                    a1 = fmaf((float)h0.y, w4.y, a1);
                    a2 = fmaf((float)h1.x, w4.z, a2);
                    a3 = fmaf((float)h1.y, w4.w, a3);
                }
            }
            const uint bw = s_bh[f >> 1];
            const float bias = (f & 1) ? h2hi(bw) : h2lo(bw);
            ((ushort*)s_c5u)[img*(C5_IMGU*2) + f] =
                f16rn(fast_tanh((a0+a1)+(a2+a3) + bias));
        }
    }
    __syncthreads();

    // ---- stage 5: f6 (84x120) + tanh -> s_f6 fp32 (aliases dead p1) ----
    #pragma unroll
    for (int it=0; it<2; it++) {
        const int id2 = tid + THREADS*it;
        if (id2 < 84*IMGS) {
            const int j = id2 >> 2, img = id2 & 3;
            const uint* cr = s_c5u + img * C5_IMGU;
            float a0=0.f, a1=0.f, a2=0.f, a3=0.f;
            if constexpr (H) {
                const uint4* wr = (const uint4*)(wsh + 48000 + j*120); // 15 x uint4
                #pragma unroll
                for (int k=0;k<15;k++) {
                    uint4 w4 = wr[k];
                    a0 = fdot2(cr[4*k],   w4.x, a0);
                    a1 = fdot2(cr[4*k+1], w4.y, a1);
                    a2 = fdot2(cr[4*k+2], w4.z, a2);
                    a3 = fdot2(cr[4*k+3], w4.w, a3);
                }
            } else {
                const float2* wr = (const float2*)(f6_w + j*120);
                #pragma unroll
                for (int k=0;k<60;k++) {
                    float2 w2 = wr[k];
                    h2 hp = __builtin_bit_cast(h2, cr[k]);
                    a0 = fmaf((float)hp.x, w2.x, a0);
                    a1 = fmaf((float)hp.y, w2.y, a1);
                }
            }
            const uint bw = s_bh[60 + (j >> 1)];
            const float bias = (j & 1) ? h2hi(bw) : h2lo(bw);
            s_f6[img*84 + j] = fast_tanh((a0+a1)+(a2+a3) + bias);
        }
    }
    __syncthreads();

    // ---- stage 6: out (10x84) -> global ----
    if (tid < 10*IMGS) {
        const int j = tid >> 2, img = tid & 3;
        const float* wr = out_w + j*84;
        const float* fr = s_f6 + img*84;
        float a0=0.f,a1=0.f,a2=0.f,a3=0.f;
        #pragma unroll
        for (int k=0;k<84;k+=4) {
            a0=fmaf(wr[k],  fr[k],  a0); a1=fmaf(wr[k+1],fr[k+1],a1);
            a2=fmaf(wr[k+2],fr[k+2],a2); a3=fmaf(wr[k+3],fr[k+3],a3);
        }
        out[((size_t)blk*IMGS + img)*10 + j] = (a0+a1)+(a2+a3) + out_b[j];
    }
}

extern "C" void kernel_launch(void* const* d_in, const int* in_sizes, int n_in,
                              void* d_out, int out_size, void* d_ws, size_t ws_size,
                              hipStream_t stream) {
    const float* x    = (const float*)d_in[0];
    const float* c1w  = (const float*)d_in[1];
    const float* c1b  = (const float*)d_in[2];
    const float* fsw  = (const float*)d_in[3];
    const float* fsb  = (const float*)d_in[4];
    const float* scw  = (const float*)d_in[5];
    const float* scb  = (const float*)d_in[6];
    const float* thw  = (const float*)d_in[7];
    const float* thb  = (const float*)d_in[8];
    const float* fow  = (const float*)d_in[9];
    const float* fob  = (const float*)d_in[10];
    const float* c5w  = (const float*)d_in[11];
    const float* c5b  = (const float*)d_in[12];
    const float* f6w  = (const float*)d_in[13];
    const float* f6b  = (const float*)d_in[14];
    const float* outw = (const float*)d_in[15];
    const float* outb = (const float*)d_in[16];
    float* outp = (float*)d_out;

    const int B = in_sizes[0] / 1024;     // 16384
    const int nblk = B / IMGS;            // 4096
    const size_t ws_need = (48000 + 10080) * sizeof(ushort);

    if (ws_size >= ws_need) {
        ushort* wsh = (ushort*)d_ws;
        cvt_w16<<<188, 256, 0, stream>>>(c5w, f6w, wsh);
        lenet_fused<true><<<nblk, THREADS, 0, stream>>>(
            x, c1w, c1b, fsw, fsb, scw, scb, thw, thb, fow, fob,
            c5w, c5b, f6w, f6b, outw, outb, wsh, outp);
    } else {
        lenet_fused<false><<<nblk, THREADS, 0, stream>>>(
            x, c1w, c1b, fsw, fsb, scw, scb, thw, thb, fow, fob,
            c5w, c5b, f6w, f6b, outw, outb, (const ushort*)nullptr, outp);
    }
}

// Round 10
// 199.905 us; speedup vs baseline: 2.6248x; 1.0074x over previous
//
#include <hip/hip_runtime.h>
#include <hip/hip_fp16.h>

#define THREADS 256
#define IMGS 4

// s_w (fp32): c1b[0..5], group biases [6..9]
#define O_C1B 0
#define O_GB  6

// p1 fp16 layout (uint units): ch stride mod32=9, img stride mod32=22 -> full bank spread
#define P1_CHU 105
#define P1_IMGU 630
// p2 fp16: 201 uints/img (402 halves, 400 used), mod32=9
#define P2_IMGU 201
// c5 fp16: 61 uints/img (122 halves, 120 used), mod32=29
#define C5_IMGU 61

typedef _Float16 h2 __attribute__((ext_vector_type(2)));

__device__ __forceinline__ float fdot2(uint a, uint b, float c) {
    return __builtin_amdgcn_fdot2(__builtin_bit_cast(h2, a), __builtin_bit_cast(h2, b), c, false);
}
__device__ __forceinline__ uint pkh2(float a, float b) {
    return __builtin_bit_cast(uint, __builtin_amdgcn_cvt_pkrtz(a, b));
}
__device__ __forceinline__ ushort f16rn(float a) {
    _Float16 h = (_Float16)a;
    return __builtin_bit_cast(ushort, h);
}
__device__ __forceinline__ float h2lo(uint w){ return (float)__builtin_bit_cast(h2, w).x; }
__device__ __forceinline__ float h2hi(uint w){ return (float)__builtin_bit_cast(h2, w).y; }

// packed f16 fma: v_pk_fma_f16 (true 2 MAC/inst)
__device__ __forceinline__ uint hfma2u(uint a, uint b, uint c) {
    __half2 r = __hfma2(__builtin_bit_cast(__half2, a),
                        __builtin_bit_cast(__half2, b),
                        __builtin_bit_cast(__half2, c));
    return __builtin_bit_cast(uint, r);
}
// broadcast lo/hi half to both lanes: one v_perm_b32
__device__ __forceinline__ uint dup_lo(uint u){ return __builtin_amdgcn_perm(u, u, 0x01000100u); }
__device__ __forceinline__ uint dup_hi(uint u){ return __builtin_amdgcn_perm(u, u, 0x03020302u); }

// (hi:lo) >> 16 -> one v_alignbit_b32
__device__ __forceinline__ uint funnel16(uint hi, uint lo) {
    return __builtin_amdgcn_alignbit(hi, lo, 16);
}

__device__ __forceinline__ float fast_tanh(float v) {
    float e = __expf(2.f * v);
    return 1.f - __fdividef(2.f, e + 1.f);
}

// load one 6-half row: q = aligned pairs, s = shifted-by-1 pairs
__device__ __forceinline__ void ld_row(const uint* p, uint* q, uint* s) {
    uint a = p[0], b = p[1], c = p[2];
    q[0] = a; q[1] = b; q[2] = c;
    s[0] = funnel16(b, a);
    s[1] = funnel16(c, b);
    s[2] = c >> 16;
}

// grouped-C3 tables
__device__ __forceinline__ int g3_ncin(int o){ return o<6?3:(o<15?4:6); }
__device__ __forceinline__ int g3_slot(int o,int j){
    return o<6 ? 6+j : (o<12 ? 9+j : (o<15 ? 13+j : 17+j));
}
__device__ __forceinline__ int g3_bi(int o){ return o<6?0:(o<12?1:(o<15?2:3)); }
__device__ __forceinline__ int g3_ch(int o,int j){
    if (o<6)  return (o+j)%6;
    if (o<12) return (o-6+j)%6;
    if (o<15) return (o-12 + j + (j>=2?1:0))%6;
    return j;
}
// stage-3 position->output map: heavy outputs first, light (ncin=3) tail
__device__ __forceinline__ int g3_omap(int p){
    return (p==0) ? 15 : (p<10 ? p+5 : p-10);
}

// pre-kernel: convert c5_w / f6_w to fp16 in workspace (RN)
__global__ __launch_bounds__(256)
void cvt_w16(const float* __restrict__ c5w, const float* __restrict__ f6w,
             ushort* __restrict__ ws) {
    int i = blockIdx.x * 256 + threadIdx.x;
    if (i < 48000) ws[i] = f16rn(c5w[i]);
    if (i < 10080) ws[48000 + i] = f16rn(f6w[i]);
}

template<bool H>
__global__ __launch_bounds__(THREADS)
void lenet_fused(const float* __restrict__ x,
                 const float* __restrict__ c1_w, const float* __restrict__ c1_b,
                 const float* __restrict__ fs_w, const float* __restrict__ fs_b,
                 const float* __restrict__ sc_w, const float* __restrict__ sc_b,
                 const float* __restrict__ th_w, const float* __restrict__ th_b,
                 const float* __restrict__ fo_w, const float* __restrict__ fo_b,
                 const float* __restrict__ c5_w, const float* __restrict__ c5_b,
                 const float* __restrict__ f6_w, const float* __restrict__ f6_b,
                 const float* __restrict__ out_w, const float* __restrict__ out_b,
                 const ushort* __restrict__ wsh,
                 float* __restrict__ out)
{
    __shared__ uint  s_p1h[IMGS * P1_IMGU];   // 10080 B; f6 (fp32) aliases after stage 4
    __shared__ uint  s_whu[23 * 16];          // 1472 B packed fp16 conv weights (row-padded)
    __shared__ float s_w[10];                 // 40 B fp32 biases (c1b, group)
    __shared__ uint  s_bh[102];               // 408 B fp16 biases: c5b [0..59], f6b [60..101]
    __shared__ uint  s_u[IMGS * 512];         // 8192 B union:
                                              //  stages 1-2: x fp16 (2048 uints)
                                              //  stages 3-5: p2h [0..803], c5h [804..1047]
    uint*  s_xh  = s_u;
    uint*  s_c5u = s_u + IMGS * P2_IMGU;
    float* s_f6  = (float*)s_p1h;

    const int tid = threadIdx.x;
    const int blk = blockIdx.x;

    // ---- stage 0a: biases -> LDS ----
    if (tid < 6)  s_w[O_C1B + tid] = c1_b[tid];
    if (tid == 0){ s_w[O_GB+0]=fs_b[0]; s_w[O_GB+1]=sc_b[0]; s_w[O_GB+2]=th_b[0]; s_w[O_GB+3]=fo_b[0]; }
    if (tid < 60) s_bh[tid]      = pkh2(c5_b[2*tid], c5_b[2*tid+1]);
    if (tid < 42) s_bh[60 + tid] = pkh2(f6_b[2*tid], f6_b[2*tid+1]);

    // ---- stage 0b: conv weights -> packed fp16, row-padded (slot = 16 uints) ----
    if (tid < 23) {
        const float* src;
        if      (tid < 6)  src = c1_w + tid*25;
        else if (tid < 9)  src = fs_w + (tid-6)*25;
        else if (tid < 13) src = sc_w + (tid-9)*25;
        else if (tid < 17) src = th_w + (tid-13)*25;
        else               src = fo_w + (tid-17)*25;
        uint* dst = s_whu + tid*16;
        #pragma unroll
        for (int ky=0; ky<5; ky++) {
            dst[ky*3+0] = pkh2(src[ky*5+0], src[ky*5+1]);
            dst[ky*3+1] = pkh2(src[ky*5+2], src[ky*5+3]);
            dst[ky*3+2] = pkh2(src[ky*5+4], 0.f);
        }
    }

    // ---- stage 1: x -> LDS as fp16 pairs ----
    {
        const float4* xg = (const float4*)(x + (size_t)blk*(IMGS*1024));
        uint2* sx = (uint2*)s_u;
        #pragma unroll
        for (int i=0;i<(IMGS*1024/4)/THREADS;i++) {
            float4 v = xg[tid + i*THREADS];
            sx[tid + i*THREADS] = make_uint2(pkh2(v.x,v.y), pkh2(v.z,v.w));
        }
    }
    __syncthreads();

    // ---- stage 2: conv1 + tanh + 2x2 avgpool -> s_p1h (fp16) ----
    for (int idx=tid; idx<IMGS*84; idx+=THREADS) {
        const int img = idx/84, r2 = idx%84, c = r2/14, pw = r2%14;
        const uint* xim = s_xh + img*512 + pw;
        uint wp[5][3];
        #pragma unroll
        for (int k=0;k<15;k++) ((uint*)wp)[k] = s_whu[c*16 + k];
        const float bias = s_w[O_C1B + c];
        uint q[6][3], s[6][3];
        #pragma unroll
        for (int r=0;r<4;r++) ld_row(xim + r*16, q[r], s[r]);
        ushort* p1o = (ushort*)s_p1h + img*(P1_IMGU*2) + c*(P1_CHU*2) + pw;
        #pragma unroll
        for (int ph=0; ph<14; ph++) {
            ld_row(xim + (2*ph+4)*16, q[(2*ph+4)%6], s[(2*ph+4)%6]);
            ld_row(xim + (2*ph+5)*16, q[(2*ph+5)%6], s[(2*ph+5)%6]);
            float sum = 0.f;
            #pragma unroll
            for (int dy=0; dy<2; dy++)
            #pragma unroll
            for (int dx=0; dx<2; dx++) {
                float t = bias;
                #pragma unroll
                for (int ky=0; ky<5; ky++) {
                    const int sl = (2*ph+dy+ky)%6;
                    const uint* rr = dx ? s[sl] : q[sl];
                    t = fdot2(rr[0], wp[ky][0], t);
                    t = fdot2(rr[1], wp[ky][1], t);
                    t = fdot2(rr[2], wp[ky][2], t);
                }
                sum += fast_tanh(t);
            }
            p1o[ph*14] = f16rn(0.25f*sum);
        }
    }
    __syncthreads();

    // ---- stage 3: grouped C3 via v_pk_fma_f16 + tanh + 2x2 avgpool -> p2 fp16 ----
    // f16 pair accumulators (col0,col1) chunked per input channel, f32 flush
    for (int idx=tid; idx<IMGS*80; idx+=THREADS) {
        const int p = idx/(IMGS*5), r2 = idx%(IMGS*5), img = r2/5, pw = r2%5;
        const int o = g3_omap(p);
        const int ncin = g3_ncin(o);
        const float bias = s_w[O_GB + g3_bi(o)];
        float acc0[10], acc1[10];
        #pragma unroll
        for (int h=0;h<10;h++){ acc0[h]=bias; acc1[h]=bias; }
        for (int j=0;j<ncin;j++) {
            const uint* p1c = s_p1h + img*P1_IMGU + g3_ch(o,j)*P1_CHU + pw;
            const int slot = g3_slot(o,j);
            uint wd[25];
            #pragma unroll
            for (int ky=0; ky<5; ky++) {
                uint u0 = s_whu[slot*16 + ky*3+0];
                uint u1 = s_whu[slot*16 + ky*3+1];
                uint u2 = s_whu[slot*16 + ky*3+2];
                wd[ky*5+0] = dup_lo(u0); wd[ky*5+1] = dup_hi(u0);
                wd[ky*5+2] = dup_lo(u1); wd[ky*5+3] = dup_hi(u1);
                wd[ky*5+4] = dup_lo(u2);
            }
            uint accp[10];
            #pragma unroll
            for (int h=0;h<10;h++) accp[h] = 0u;
            #pragma unroll
            for (int r=0;r<14;r++) {
                uint a = p1c[r*7], b = p1c[r*7+1], cc = p1c[r*7+2];
                uint s1 = funnel16(b, a);
                uint s3 = funnel16(cc, b);
                const uint P0=a, P1=s1, P2=b, P3=s3, P4=cc;
                #pragma unroll
                for (int ky=0;ky<5;ky++) {
                    const int hh = r - ky;
                    if (hh >= 0 && hh < 10) {
                        accp[hh] = hfma2u(P0, wd[ky*5+0], accp[hh]);
                        accp[hh] = hfma2u(P1, wd[ky*5+1], accp[hh]);
                        accp[hh] = hfma2u(P2, wd[ky*5+2], accp[hh]);
                        accp[hh] = hfma2u(P3, wd[ky*5+3], accp[hh]);
                        accp[hh] = hfma2u(P4, wd[ky*5+4], accp[hh]);
                    }
                }
            }
            #pragma unroll
            for (int h=0;h<10;h++) {
                acc0[h] += h2lo(accp[h]);
                acc1[h] += h2hi(accp[h]);
            }
        }
        ushort* p2o = (ushort*)s_u + img*(P2_IMGU*2) + o*25 + pw;
        #pragma unroll
        for (int ph=0; ph<5; ph++) {
            float t = fast_tanh(acc0[2*ph])   + fast_tanh(acc1[2*ph])
                    + fast_tanh(acc0[2*ph+1]) + fast_tanh(acc1[2*ph+1]);
            p2o[ph*5] = f16rn(0.25f*t);
        }
    }
    __syncthreads();

    // ---- stage 4: conv5 = 120x400 matvec + tanh -> c5 fp16 ----
    #pragma unroll
    for (int it=0; it<2; it++) {
        const int id2 = tid + THREADS*it;
        if (id2 < 120*IMGS) {
            const int f = id2 >> 2, img = id2 & 3;
            const uint* pr = s_u + img * P2_IMGU;
            float a0=0.f, a1=0.f, a2=0.f, a3=0.f;
            if constexpr (H) {
                const uint4* wr = (const uint4*)(wsh + f*400);   // 50 x uint4 = 400 halves
                #pragma unroll 5
                for (int k=0;k<50;k++) {
                    uint4 w4 = wr[k];
                    a0 = fdot2(pr[4*k],   w4.x, a0);
                    a1 = fdot2(pr[4*k+1], w4.y, a1);
                    a2 = fdot2(pr[4*k+2], w4.z, a2);
                    a3 = fdot2(pr[4*k+3], w4.w, a3);
                }
            } else {
                const float4* wr = (const float4*)(c5_w + f*400);
                #pragma unroll 4
                for (int k=0;k<100;k++) {
                    float4 w4 = wr[k];
                    h2 h0 = __builtin_bit_cast(h2, pr[2*k]);
                    h2 h1 = __builtin_bit_cast(h2, pr[2*k+1]);
                    a0 = fmaf((float)h0.x, w4.x, a0);
                    a1 = fmaf((float)h0.y, w4.y, a1);
                    a2 = fmaf((float)h1.x, w4.z, a2);
                    a3 = fmaf((float)h1.y, w4.w, a3);
                }
            }
            const uint bw = s_bh[f >> 1];
            const float bias = (f & 1) ? h2hi(bw) : h2lo(bw);
            ((ushort*)s_c5u)[img*(C5_IMGU*2) + f] =
                f16rn(fast_tanh((a0+a1)+(a2+a3) + bias));
        }
    }
    __syncthreads();

    // ---- stage 5: f6 (84x120) + tanh -> s_f6 fp32 (aliases dead p1) ----
    #pragma unroll
    for (int it=0; it<2; it++) {
        const int id2 = tid + THREADS*it;
        if (id2 < 84*IMGS) {
            const int j = id2 >> 2, img = id2 & 3;
            const uint* cr = s_c5u + img * C5_IMGU;
            float a0=0.f, a1=0.f, a2=0.f, a3=0.f;
            if constexpr (H) {
                const uint4* wr = (const uint4*)(wsh + 48000 + j*120); // 15 x uint4
                #pragma unroll
                for (int k=0;k<15;k++) {
                    uint4 w4 = wr[k];
                    a0 = fdot2(cr[4*k],   w4.x, a0);
                    a1 = fdot2(cr[4*k+1], w4.y, a1);
                    a2 = fdot2(cr[4*k+2], w4.z, a2);
                    a3 = fdot2(cr[4*k+3], w4.w, a3);
                }
            } else {
                const float2* wr = (const float2*)(f6_w + j*120);
                #pragma unroll
                for (int k=0;k<60;k++) {
                    float2 w2 = wr[k];
                    h2 hp = __builtin_bit_cast(h2, cr[k]);
                    a0 = fmaf((float)hp.x, w2.x, a0);
                    a1 = fmaf((float)hp.y, w2.y, a1);
                }
            }
            const uint bw = s_bh[60 + (j >> 1)];
            const float bias = (j & 1) ? h2hi(bw) : h2lo(bw);
            s_f6[img*84 + j] = fast_tanh((a0+a1)+(a2+a3) + bias);
        }
    }
    __syncthreads();

    // ---- stage 6: out (10x84) -> global ----
    if (tid < 10*IMGS) {
        const int j = tid >> 2, img = tid & 3;
        const float* wr = out_w + j*84;
        const float* fr = s_f6 + img*84;
        float a0=0.f,a1=0.f,a2=0.f,a3=0.f;
        #pragma unroll
        for (int k=0;k<84;k+=4) {
            a0=fmaf(wr[k],  fr[k],  a0); a1=fmaf(wr[k+1],fr[k+1],a1);
            a2=fmaf(wr[k+2],fr[k+2],a2); a3=fmaf(wr[k+3],fr[k+3],a3);
        }
        out[((size_t)blk*IMGS + img)*10 + j] = (a0+a1)+(a2+a3) + out_b[j];
    }
}

extern "C" void kernel_launch(void* const* d_in, const int* in_sizes, int n_in,
                              void* d_out, int out_size, void* d_ws, size_t ws_size,
                              hipStream_t stream) {
    const float* x    = (const float*)d_in[0];
    const float* c1w  = (const float*)d_in[1];
    const float* c1b  = (const float*)d_in[2];
    const float* fsw  = (const float*)d_in[3];
    const float* fsb  = (const float*)d_in[4];
    const float* scw  = (const float*)d_in[5];
    const float* scb  = (const float*)d_in[6];
    const float* thw  = (const float*)d_in[7];
    const float* thb  = (const float*)d_in[8];
    const float* fow  = (const float*)d_in[9];
    const float* fob  = (const float*)d_in[10];
    const float* c5w  = (const float*)d_in[11];
    const float* c5b  = (const float*)d_in[12];
    const float* f6w  = (const float*)d_in[13];
    const float* f6b  = (const float*)d_in[14];
    const float* outw = (const float*)d_in[15];
    const float* outb = (const float*)d_in[16];
    float* outp = (float*)d_out;

    const int B = in_sizes[0] / 1024;     // 16384
    const int nblk = B / IMGS;            // 4096
    const size_t ws_need = (48000 + 10080) * sizeof(ushort);

    if (ws_size >= ws_need) {
        ushort* wsh = (ushort*)d_ws;
        cvt_w16<<<188, 256, 0, stream>>>(c5w, f6w, wsh);
        lenet_fused<true><<<nblk, THREADS, 0, stream>>>(
            x, c1w, c1b, fsw, fsb, scw, scb, thw, thb, fow, fob,
            c5w, c5b, f6w, f6b, outw, outb, wsh, outp);
    } else {
        lenet_fused<false><<<nblk, THREADS, 0, stream>>>(
            x, c1w, c1b, fsw, fsb, scw, scb, thw, thb, fow, fob,
            c5w, c5b, f6w, f6b, outw, outb, (const ushort*)nullptr, outp);
    }
}

// Round 11
// 198.579 us; speedup vs baseline: 2.6424x; 1.0067x over previous
//
#include <hip/hip_runtime.h>
#include <hip/hip_fp16.h>

#define THREADS 256
#define IMGS 4

// s_w (fp32): c1b[0..5], group biases [6..9]
#define O_C1B 0
#define O_GB  6

// p1 fp16 layout (uint units): ch stride mod32=9, img stride mod32=22 -> full bank spread
#define P1_CHU 105
#define P1_IMGU 630
// p2 fp16: 201 uints/img (402 halves, 400 used), mod32=9
#define P2_IMGU 201
// c5 fp16: 61 uints/img (122 halves, 120 used), mod32=29
#define C5_IMGU 61

typedef _Float16 h2 __attribute__((ext_vector_type(2)));

__device__ __forceinline__ float fdot2(uint a, uint b, float c) {
    return __builtin_amdgcn_fdot2(__builtin_bit_cast(h2, a), __builtin_bit_cast(h2, b), c, false);
}
__device__ __forceinline__ uint pkh2(float a, float b) {
    return __builtin_bit_cast(uint, __builtin_amdgcn_cvt_pkrtz(a, b));
}
__device__ __forceinline__ ushort f16rn(float a) {
    _Float16 h = (_Float16)a;
    return __builtin_bit_cast(ushort, h);
}
__device__ __forceinline__ float h2lo(uint w){ return (float)__builtin_bit_cast(h2, w).x; }
__device__ __forceinline__ float h2hi(uint w){ return (float)__builtin_bit_cast(h2, w).y; }

// packed f16 fma: v_pk_fma_f16 (2 MAC/inst)
__device__ __forceinline__ uint hfma2u(uint a, uint b, uint c) {
    __half2 r = __hfma2(__builtin_bit_cast(__half2, a),
                        __builtin_bit_cast(__half2, b),
                        __builtin_bit_cast(__half2, c));
    return __builtin_bit_cast(uint, r);
}

// (hi:lo) >> 16 -> one v_alignbit_b32
__device__ __forceinline__ uint funnel16(uint hi, uint lo) {
    return __builtin_amdgcn_alignbit(hi, lo, 16);
}

__device__ __forceinline__ float fast_tanh(float v) {
    float e = __expf(2.f * v);
    return 1.f - __fdividef(2.f, e + 1.f);
}

// load one 6-half row: q = aligned pairs, s = shifted-by-1 pairs
__device__ __forceinline__ void ld_row(const uint* p, uint* q, uint* s) {
    uint a = p[0], b = p[1], c = p[2];
    q[0] = a; q[1] = b; q[2] = c;
    s[0] = funnel16(b, a);
    s[1] = funnel16(c, b);
    s[2] = c >> 16;
}

// grouped-C3 tables
__device__ __forceinline__ int g3_ncin(int o){ return o<6?3:(o<15?4:6); }
__device__ __forceinline__ int g3_slot(int o,int j){
    return o<6 ? 6+j : (o<12 ? 9+j : (o<15 ? 13+j : 17+j));
}
__device__ __forceinline__ int g3_bi(int o){ return o<6?0:(o<12?1:(o<15?2:3)); }
__device__ __forceinline__ int g3_ch(int o,int j){
    if (o<6)  return (o+j)%6;
    if (o<12) return (o-6+j)%6;
    if (o<15) return (o-12 + j + (j>=2?1:0))%6;
    return j;
}
// stage-3 position->output map: heavy outputs first, light (ncin=3) tail
__device__ __forceinline__ int g3_omap(int p){
    return (p==0) ? 15 : (p<10 ? p+5 : p-10);
}

// pre-kernel: convert c5_w / f6_w to fp16 in workspace (RN)
__global__ __launch_bounds__(256)
void cvt_w16(const float* __restrict__ c5w, const float* __restrict__ f6w,
             ushort* __restrict__ ws) {
    int i = blockIdx.x * 256 + threadIdx.x;
    if (i < 48000) ws[i] = f16rn(c5w[i]);
    if (i < 10080) ws[48000 + i] = f16rn(f6w[i]);
}

template<bool H>
__global__ __launch_bounds__(THREADS, 4)   // 128-VGPR budget: let arrays live in regs
void lenet_fused(const float* __restrict__ x,
                 const float* __restrict__ c1_w, const float* __restrict__ c1_b,
                 const float* __restrict__ fs_w, const float* __restrict__ fs_b,
                 const float* __restrict__ sc_w, const float* __restrict__ sc_b,
                 const float* __restrict__ th_w, const float* __restrict__ th_b,
                 const float* __restrict__ fo_w, const float* __restrict__ fo_b,
                 const float* __restrict__ c5_w, const float* __restrict__ c5_b,
                 const float* __restrict__ f6_w, const float* __restrict__ f6_b,
                 const float* __restrict__ out_w, const float* __restrict__ out_b,
                 const ushort* __restrict__ wsh,
                 float* __restrict__ out)
{
    __shared__ uint  s_p1h[IMGS * P1_IMGU];   // 10080 B; f6 (fp32) aliases after stage 4
    __shared__ uint  s_whu[23 * 16];          // 1472 B packed fp16 conv weights (row-padded)
    __shared__ uint  s_wd[23 * 26];           // 2392 B dup'd pk weights (w,w) per tap
    __shared__ float s_w[10];                 // 40 B fp32 biases (c1b, group)
    __shared__ uint  s_bh[102];               // 408 B fp16 biases: c5b [0..59], f6b [60..101]
    __shared__ uint  s_u[IMGS * 512];         // 8192 B union:
                                              //  stages 1-2: x fp16 (2048 uints)
                                              //  stages 3-5: p2h [0..803], c5h [804..1047]
    uint*  s_xh  = s_u;
    uint*  s_c5u = s_u + IMGS * P2_IMGU;
    float* s_f6  = (float*)s_p1h;

    const int tid = threadIdx.x;
    const int blk = blockIdx.x;

    // ---- stage 0a: biases -> LDS ----
    if (tid < 6)  s_w[O_C1B + tid] = c1_b[tid];
    if (tid == 0){ s_w[O_GB+0]=fs_b[0]; s_w[O_GB+1]=sc_b[0]; s_w[O_GB+2]=th_b[0]; s_w[O_GB+3]=fo_b[0]; }
    if (tid < 60) s_bh[tid]      = pkh2(c5_b[2*tid], c5_b[2*tid+1]);
    if (tid < 42) s_bh[60 + tid] = pkh2(f6_b[2*tid], f6_b[2*tid+1]);

    // ---- stage 0b: conv weights -> packed fp16 (pairs) + dup'd pk form ----
    if (tid < 23) {
        const float* src;
        if      (tid < 6)  src = c1_w + tid*25;
        else if (tid < 9)  src = fs_w + (tid-6)*25;
        else if (tid < 13) src = sc_w + (tid-9)*25;
        else if (tid < 17) src = th_w + (tid-13)*25;
        else               src = fo_w + (tid-17)*25;
        uint* dst = s_whu + tid*16;
        #pragma unroll
        for (int ky=0; ky<5; ky++) {
            dst[ky*3+0] = pkh2(src[ky*5+0], src[ky*5+1]);
            dst[ky*3+1] = pkh2(src[ky*5+2], src[ky*5+3]);
            dst[ky*3+2] = pkh2(src[ky*5+4], 0.f);
        }
        uint* dd = s_wd + tid*26;
        #pragma unroll
        for (int t=0; t<25; t++) {
            float v = src[t];
            dd[t] = pkh2(v, v);
        }
    }

    // ---- stage 1: x -> LDS as fp16 pairs ----
    {
        const float4* xg = (const float4*)(x + (size_t)blk*(IMGS*1024));
        uint2* sx = (uint2*)s_u;
        #pragma unroll
        for (int i=0;i<(IMGS*1024/4)/THREADS;i++) {
            float4 v = xg[tid + i*THREADS];
            sx[tid + i*THREADS] = make_uint2(pkh2(v.x,v.y), pkh2(v.z,v.w));
        }
    }
    __syncthreads();

    // ---- stage 2: conv1 + tanh + 2x2 avgpool -> s_p1h (fp16) ----
    for (int idx=tid; idx<IMGS*84; idx+=THREADS) {
        const int img = idx/84, r2 = idx%84, c = r2/14, pw = r2%14;
        const uint* xim = s_xh + img*512 + pw;
        uint wp[5][3];
        #pragma unroll
        for (int k=0;k<15;k++) ((uint*)wp)[k] = s_whu[c*16 + k];
        const float bias = s_w[O_C1B + c];
        uint q[6][3], s[6][3];
        #pragma unroll
        for (int r=0;r<4;r++) ld_row(xim + r*16, q[r], s[r]);
        ushort* p1o = (ushort*)s_p1h + img*(P1_IMGU*2) + c*(P1_CHU*2) + pw;
        #pragma unroll
        for (int ph=0; ph<14; ph++) {
            ld_row(xim + (2*ph+4)*16, q[(2*ph+4)%6], s[(2*ph+4)%6]);
            ld_row(xim + (2*ph+5)*16, q[(2*ph+5)%6], s[(2*ph+5)%6]);
            float sum = 0.f;
            #pragma unroll
            for (int dy=0; dy<2; dy++)
            #pragma unroll
            for (int dx=0; dx<2; dx++) {
                float t = bias;
                #pragma unroll
                for (int ky=0; ky<5; ky++) {
                    const int sl = (2*ph+dy+ky)%6;
                    const uint* rr = dx ? s[sl] : q[sl];
                    t = fdot2(rr[0], wp[ky][0], t);
                    t = fdot2(rr[1], wp[ky][1], t);
                    t = fdot2(rr[2], wp[ky][2], t);
                }
                sum += fast_tanh(t);
            }
            p1o[ph*14] = f16rn(0.25f*sum);
        }
    }
    __syncthreads();

    // ---- stage 3: grouped C3 via v_pk_fma_f16 + tanh + 2x2 avgpool -> p2 fp16 ----
    // f16 pair accumulators (col0,col1) chunked per input channel, f32 flush
    for (int idx=tid; idx<IMGS*80; idx+=THREADS) {
        const int p = idx/(IMGS*5), r2 = idx%(IMGS*5), img = r2/5, pw = r2%5;
        const int o = g3_omap(p);
        const int ncin = g3_ncin(o);
        const float bias = s_w[O_GB + g3_bi(o)];
        float acc0[10], acc1[10];
        #pragma unroll
        for (int h=0;h<10;h++){ acc0[h]=bias; acc1[h]=bias; }
        for (int j=0;j<ncin;j++) {
            const uint* p1c = s_p1h + img*P1_IMGU + g3_ch(o,j)*P1_CHU + pw;
            const int slot = g3_slot(o,j);
            uint wd[25];
            #pragma unroll
            for (int t=0;t<25;t++) wd[t] = s_wd[slot*26 + t];
            uint accp[10];
            #pragma unroll
            for (int h=0;h<10;h++) accp[h] = 0u;
            #pragma unroll
            for (int r=0;r<14;r++) {
                uint a = p1c[r*7], b = p1c[r*7+1], cc = p1c[r*7+2];
                uint s1 = funnel16(b, a);
                uint s3 = funnel16(cc, b);
                const uint P0=a, P1=s1, P2=b, P3=s3, P4=cc;
                #pragma unroll
                for (int ky=0;ky<5;ky++) {
                    const int hh = r - ky;
                    if (hh >= 0 && hh < 10) {
                        accp[hh] = hfma2u(P0, wd[ky*5+0], accp[hh]);
                        accp[hh] = hfma2u(P1, wd[ky*5+1], accp[hh]);
                        accp[hh] = hfma2u(P2, wd[ky*5+2], accp[hh]);
                        accp[hh] = hfma2u(P3, wd[ky*5+3], accp[hh]);
                        accp[hh] = hfma2u(P4, wd[ky*5+4], accp[hh]);
                    }
                }
            }
            #pragma unroll
            for (int h=0;h<10;h++) {
                acc0[h] += h2lo(accp[h]);
                acc1[h] += h2hi(accp[h]);
            }
        }
        ushort* p2o = (ushort*)s_u + img*(P2_IMGU*2) + o*25 + pw;
        #pragma unroll
        for (int ph=0; ph<5; ph++) {
            float t = fast_tanh(acc0[2*ph])   + fast_tanh(acc1[2*ph])
                    + fast_tanh(acc0[2*ph+1]) + fast_tanh(acc1[2*ph+1]);
            p2o[ph*5] = f16rn(0.25f*t);
        }
    }
    __syncthreads();

    // ---- stage 4: conv5 = 120x400 matvec + tanh -> c5 fp16 ----
    #pragma unroll
    for (int it=0; it<2; it++) {
        const int id2 = tid + THREADS*it;
        if (id2 < 120*IMGS) {
            const int f = id2 >> 2, img = id2 & 3;
            const uint* pr = s_u + img * P2_IMGU;
            float a0=0.f, a1=0.f, a2=0.f, a3=0.f;
            if constexpr (H) {
                const uint4* wr = (const uint4*)(wsh + f*400);   // 50 x uint4 = 400 halves
                #pragma unroll 5
                for (int k=0;k<50;k++) {
                    uint4 w4 = wr[k];
                    a0 = fdot2(pr[4*k],   w4.x, a0);
                    a1 = fdot2(pr[4*k+1], w4.y, a1);
                    a2 = fdot2(pr[4*k+2], w4.z, a2);
                    a3 = fdot2(pr[4*k+3], w4.w, a3);
                }
            } else {
                const float4* wr = (const float4*)(c5_w + f*400);
                #pragma unroll 4
                for (int k=0;k<100;k++) {
                    float4 w4 = wr[k];
                    h2 h0 = __builtin_bit_cast(h2, pr[2*k]);
                    h2 h1 = __builtin_bit_cast(h2, pr[2*k+1]);
                    a0 = fmaf((float)h0.x, w4.x, a0);
                    a1 = fmaf((float)h0.y, w4.y, a1);
                    a2 = fmaf((float)h1.x, w4.z, a2);
                    a3 = fmaf((float)h1.y, w4.w, a3);
                }
            }
            const uint bw = s_bh[f >> 1];
            const float bias = (f & 1) ? h2hi(bw) : h2lo(bw);
            ((ushort*)s_c5u)[img*(C5_IMGU*2) + f] =
                f16rn(fast_tanh((a0+a1)+(a2+a3) + bias));
        }
    }
    __syncthreads();

    // ---- stage 5: f6 (84x120) + tanh -> s_f6 fp32 (aliases dead p1) ----
    #pragma unroll
    for (int it=0; it<2; it++) {
        const int id2 = tid + THREADS*it;
        if (id2 < 84*IMGS) {
            const int j = id2 >> 2, img = id2 & 3;
            const uint* cr = s_c5u + img * C5_IMGU;
            float a0=0.f, a1=0.f, a2=0.f, a3=0.f;
            if constexpr (H) {
                const uint4* wr = (const uint4*)(wsh + 48000 + j*120); // 15 x uint4
                #pragma unroll
                for (int k=0;k<15;k++) {
                    uint4 w4 = wr[k];
                    a0 = fdot2(cr[4*k],   w4.x, a0);
                    a1 = fdot2(cr[4*k+1], w4.y, a1);
                    a2 = fdot2(cr[4*k+2], w4.z, a2);
                    a3 = fdot2(cr[4*k+3], w4.w, a3);
                }
            } else {
                const float2* wr = (const float2*)(f6_w + j*120);
                #pragma unroll
                for (int k=0;k<60;k++) {
                    float2 w2 = wr[k];
                    h2 hp = __builtin_bit_cast(h2, cr[k]);
                    a0 = fmaf((float)hp.x, w2.x, a0);
                    a1 = fmaf((float)hp.y, w2.y, a1);
                }
            }
            const uint bw = s_bh[60 + (j >> 1)];
            const float bias = (j & 1) ? h2hi(bw) : h2lo(bw);
            s_f6[img*84 + j] = fast_tanh((a0+a1)+(a2+a3) + bias);
        }
    }
    __syncthreads();

    // ---- stage 6: out (10x84) -> global ----
    if (tid < 10*IMGS) {
        const int j = tid >> 2, img = tid & 3;
        const float* wr = out_w + j*84;
        const float* fr = s_f6 + img*84;
        float a0=0.f,a1=0.f,a2=0.f,a3=0.f;
        #pragma unroll
        for (int k=0;k<84;k+=4) {
            a0=fmaf(wr[k],  fr[k],  a0); a1=fmaf(wr[k+1],fr[k+1],a1);
            a2=fmaf(wr[k+2],fr[k+2],a2); a3=fmaf(wr[k+3],fr[k+3],a3);
        }
        out[((size_t)blk*IMGS + img)*10 + j] = (a0+a1)+(a2+a3) + out_b[j];
    }
}

extern "C" void kernel_launch(void* const* d_in, const int* in_sizes, int n_in,
                              void* d_out, int out_size, void* d_ws, size_t ws_size,
                              hipStream_t stream) {
    const float* x    = (const float*)d_in[0];
    const float* c1w  = (const float*)d_in[1];
    const float* c1b  = (const float*)d_in[2];
    const float* fsw  = (const float*)d_in[3];
    const float* fsb  = (const float*)d_in[4];
    const float* scw  = (const float*)d_in[5];
    const float* scb  = (const float*)d_in[6];
    const float* thw  = (const float*)d_in[7];
    const float* thb  = (const float*)d_in[8];
    const float* fow  = (const float*)d_in[9];
    const float* fob  = (const float*)d_in[10];
    const float* c5w  = (const float*)d_in[11];
    const float* c5b  = (const float*)d_in[12];
    const float* f6w  = (const float*)d_in[13];
    const float* f6b  = (const float*)d_in[14];
    const float* outw = (const float*)d_in[15];
    const float* outb = (const float*)d_in[16];
    float* outp = (float*)d_out;

    const int B = in_sizes[0] / 1024;     // 16384
    const int nblk = B / IMGS;            // 4096
    const size_t ws_need = (48000 + 10080) * sizeof(ushort);

    if (ws_size >= ws_need) {
        ushort* wsh = (ushort*)d_ws;
        cvt_w16<<<188, 256, 0, stream>>>(c5w, f6w, wsh);
        lenet_fused<true><<<nblk, THREADS, 0, stream>>>(
            x, c1w, c1b, fsw, fsb, scw, scb, thw, thb, fow, fob,
            c5w, c5b, f6w, f6b, outw, outb, wsh, outp);
    } else {
        lenet_fused<false><<<nblk, THREADS, 0, stream>>>(
            x, c1w, c1b, fsw, fsb, scw, scb, thw, thb, fow, fob,
            c5w, c5b, f6w, f6b, outw, outb, (const ushort*)nullptr, outp);
    }
}